// Round 13
// baseline (335.362 us; speedup 1.0000x reference)
//
#include <hip/hip_runtime.h>
#include <hip/hip_fp16.h>
#include <math.h>

#define CUTOFF 5.0f
#define H 64
#define FIN 16
#define NLAYERS 3
#define LUTN 2048          // intervals; table has LUTN+1 entries
#define LUTSTRIDE 2052     // padded per-layer stride
#define ASTRIDE 72         // LDS row stride in halves (144B, 16B-aligned)
#define MEANB 256          // blocks in mean pass (partials rows)
#define BROWS 256          // rows per sort bucket
#define NBMAX 512          // max buckets (N <= 128K)
#define MAXC 5120          // per-bucket stg stride AND LDS sort capacity (20KB)
#define ABLK 4096          // edges per pass-A block

// 1/sqrt(1 + 1e-3)  (BN inference, moving mean 0 / var 1)
#define BN_INV 0.999500374750f

typedef _Float16 h8 __attribute__((ext_vector_type(8)));
typedef _Float16 h2 __attribute__((ext_vector_type(2)));
typedef float f32x4 __attribute__((ext_vector_type(4)));
typedef unsigned int u32x2 __attribute__((ext_vector_type(2)));

__device__ __forceinline__ float softplus_f(float x) {
    return fmaxf(x, 0.f) + __logf(1.f + __expf(-fabsf(x)));
}

// ---- K_pre: fused passA + setup (embed lives in passB). Block roles:
//   [0, nbA)             passA: LDS-sorted bucket scatter (coalesced write-out)
//   [nbA, +9)            LUT: inline wsum/bsum, 1024 entries/block
//   [.., +3)             weight swizzle Wsw + b2p
__global__ __launch_bounds__(1024)
void k_pre(const float* __restrict__ fW1, const float* __restrict__ fb1,
           const float* __restrict__ fW2, const float* __restrict__ fb2,
           const float* __restrict__ iW1, const float* __restrict__ iW2,
           const float* __restrict__ bn_g, const float* __restrict__ bn_b,
           const float* __restrict__ ib2, h8* __restrict__ Wsw,
           float* __restrict__ b2p, float* __restrict__ lut,
           const int* __restrict__ ei, const float* __restrict__ dist,
           unsigned int* __restrict__ cursor, u32x2* __restrict__ stg,
           int N, int E, int NB, int nbA) {
    __shared__ u32x2 s_rec[ABLK];          // 32KB block-local sorted records
    __shared__ unsigned s_cnt[NBMAX];      // per-bucket counts
    __shared__ unsigned s_x[NBMAX];        // inclusive scan
    __shared__ unsigned s_ofs[NBMAX];      // scatter cursors
    __shared__ unsigned s_gbase[NBMAX];    // global bases (cursor-reserved)
    __shared__ float swsum[64];
    __shared__ float sbsum;
    int b = blockIdx.x;
    int t = threadIdx.x;
    if (b < nbA) {
        // ---- passA role: LDS sort by bucket, then coalesced-run write-out ----
        int e0 = b * ABLK;
        int nE = min(ABLK, E - e0);
        for (int i = t; i < NBMAX; i += 1024) s_cnt[i] = 0;
        __syncthreads();
        int rowv[4];
        unsigned rxv[4] = {0u, 0u, 0u, 0u};
#pragma unroll
        for (int j = 0; j < 4; j++) {
            int li = j * 1024 + t;
            rowv[j] = -1;
            if (li < nE) {
                int e = e0 + li;
                int r = ei[e];
                int col = ei[E + e];
                float d = dist[e];
                int didx = (int)(d * (32768.0f / CUTOFF) + 0.5f);
                didx = max(0, min(didx, 32767));
                rowv[j] = r;
                rxv[j] = ((unsigned)col << 15) | (unsigned)didx;
                atomicAdd(&s_cnt[r / BROWS], 1u);
            }
        }
        __syncthreads();
        if (t < NBMAX) s_x[t] = s_cnt[t];
        __syncthreads();
        for (int off = 1; off < NBMAX; off <<= 1) {
            unsigned v = 0;
            if (t < NBMAX && t >= off) v = s_x[t - off];
            __syncthreads();
            if (t < NBMAX) s_x[t] += v;
            __syncthreads();
        }
        if (t < NBMAX) {
            unsigned c = s_cnt[t];
            unsigned lstart = s_x[t] - c;
            s_ofs[t] = lstart;
            s_x[t] = lstart;                       // repurpose as lstart
            s_gbase[t] = (c && t < (unsigned)NB) ? atomicAdd(&cursor[t], c) : 0u;
        }
        __syncthreads();
#pragma unroll
        for (int j = 0; j < 4; j++) {
            if (rowv[j] >= 0) {
                unsigned slot = atomicAdd(&s_ofs[rowv[j] / BROWS], 1u);
                u32x2 rec;
                rec.x = rxv[j];
                rec.y = (unsigned)rowv[j];
                s_rec[slot] = rec;
            }
        }
        __syncthreads();
        // linear walk of sorted records -> per-bucket contiguous global runs
        for (int i = t; i < nE; i += 1024) {
            u32x2 rec = s_rec[i];
            int bk = (int)(rec.y / BROWS);
            unsigned g = s_gbase[bk] + ((unsigned)i - s_x[bk]);
            if (g < MAXC)                          // overflow guard (~never)
                stg[(size_t)bk * MAXC + g] = rec;
        }
    } else if (b < nbA + NLAYERS * 3) {
        // ---- LUT role ----
        int lb = b - nbA;
        int l = lb / 3, part = lb % 3;
        if (t < 64) {
            float s = 0.f;
            for (int j = 0; j < H; j++) s += fW2[l * H * H + t * H + j];
            swsum[t] = s;
        }
        if (t == 64) {
            float s = 0.f;
            for (int j = 0; j < H; j++) s += fb2[l * H + j];
            sbsum = s;
        }
        __syncthreads();
        int i = part * 1024 + t;
        if (i <= LUTN) {
            float d = (float)i * (CUTOFF / (float)LUTN);
            float scaled = d * (2.0f / CUTOFF) - 1.0f;
            float cut = 0.5f * (__cosf(d * (3.14159265358979f / CUTOFF)) + 1.0f);
            if (d > CUTOFF) cut = 0.f;
            float s = 0.f;
            for (int hh = 0; hh < H; hh++) {
                int wi = l * H + hh;
                s += tanhf(scaled * fW1[wi] + fb1[wi]) * swsum[hh];
            }
            lut[l * LUTSTRIDE + i] = cut * (s + sbsum);
        }
    } else {
        // ---- weight swizzle role ----
        int tid = (b - nbA - NLAYERS * 3) * 1024 + t;
        if (tid < NLAYERS * H)
            b2p[tid] = ib2[tid] * BN_INV * bn_g[tid] + bn_b[tid];
        if (tid < NLAYERS * 2 * 8 * 64) {
            int lane = tid & 63;
            int frag = (tid >> 6) & 7;
            int mat  = (tid >> 9) & 1;
            int l    = tid >> 10;
            int kt = frag >> 2, nt = frag & 3;
            int n = nt * 16 + (lane & 15);
            int k0 = kt * 32 + (lane >> 4) * 8;
            const float* W = (mat ? iW2 : iW1) + l * H * H;
            float scale = mat ? BN_INV * bn_g[l * H + n] : 1.0f;
            h8 v;
#pragma unroll
            for (int j = 0; j < 8; j++) v[j] = (_Float16)(W[(k0 + j) * H + n] * scale);
            Wsw[tid] = v;
        }
    }
}

// Pass B: per-bucket counting sort + row_ptr + EMBED of this bucket's rows.
// Two direct stg reads (bucket region is 16-32KB -> second read L2-hot); no
// register staging (round-10's myrec[] spilled to scratch at VGPR=32).
__global__ __launch_bounds__(1024)
void k_passB(const u32x2* __restrict__ stg, const unsigned int* __restrict__ cursor,
             int* __restrict__ row_ptr, unsigned int* __restrict__ recs,
             const float* __restrict__ x, const float* __restrict__ emb_W,
             const float* __restrict__ emb_b, _Float16* __restrict__ h0,
             int N, int NB) {
    __shared__ int s_bb[NBMAX];
    __shared__ int s_c[BROWS];
    __shared__ int s_x[BROWS];
    __shared__ unsigned s_out[MAXC];       // 20KB
    int b = blockIdx.x, t = threadIdx.x;
    // bucket counts + redundant inclusive scan over NBMAX
    if (t < NBMAX) {
        int cb = 0;
        if (t < NB) cb = min((int)cursor[t], MAXC);
        s_bb[t] = cb;
    }
    __syncthreads();
    for (int off = 1; off < NBMAX; off <<= 1) {
        int v = 0;
        if (t < NBMAX && t >= off) v = s_bb[t - off];
        __syncthreads();
        if (t < NBMAX) s_bb[t] += v;
        __syncthreads();
    }
    int bbase = (b > 0) ? s_bb[b - 1] : 0;
    int cnt = s_bb[b] - bbase;
    int r0 = b * BROWS;
    int r1 = min(r0 + BROWS, N);
    int nrows = r1 - r0;
    const u32x2* mystg = stg + (size_t)b * MAXC;
    if (t < BROWS) s_c[t] = 0;
    __syncthreads();
    // count rows (first stg read)
    for (int i = t; i < cnt; i += 1024)
        atomicAdd(&s_c[(int)mystg[i].y - r0], 1);
    __syncthreads();
    if (t < BROWS) s_x[t] = s_c[t];
    __syncthreads();
    for (int off = 1; off < BROWS; off <<= 1) {
        int v = 0;
        if (t < BROWS && t >= off) v = s_x[t - off];
        __syncthreads();
        if (t < BROWS) s_x[t] += v;
        __syncthreads();
    }
    // exclusive offsets -> row_ptr + per-row cursors
    if (t < nrows) {
        int excl = s_x[t] - s_c[t];
        row_ptr[r0 + t] = bbase + excl;
        s_c[t] = excl;
    }
    if (b == NB - 1 && t == 0) row_ptr[N] = bbase + cnt;
    __syncthreads();
    // scatter into sorted LDS order (second stg read, L2-hot)
    for (int i = t; i < cnt; i += 1024) {
        u32x2 rec = mystg[i];
        int slot = atomicAdd(&s_c[(int)rec.y - r0], 1);
        s_out[slot] = rec.x;
    }
    __syncthreads();
    for (int i = t; i < cnt; i += 1024)
        recs[bbase + i] = s_out[i];
    // ---- embed this bucket's rows: 32 threads/node, 2 lanes each ----
    for (int i = t; i < nrows * 32; i += 1024) {
        int node = r0 + (i >> 5);
        int l2 = (i & 31) * 2;
        float a0 = emb_b[l2], a1 = emb_b[l2 + 1];
#pragma unroll
        for (int k = 0; k < FIN; k++) {
            float xv = x[node * FIN + k];
            a0 += xv * emb_W[k * H + l2];
            a1 += xv * emb_W[k * H + l2 + 1];
        }
        h2 o = (h2){(_Float16)a0, (_Float16)a1};
        *(h2*)&h0[(size_t)node * H + l2] = o;
    }
}

// 4-edge clamped processing for one row: loads recs+h, lerps fv, accumulates.
#define PROC4(KK, SS, TT, ACC) do {                                          \
    int _lim = ((TT) > (SS)) ? (TT) - 1 : 0;                                 \
    int _ka = min((KK), _lim),     _kb = min((KK) + 1, _lim);                \
    int _kc = min((KK) + 2, _lim), _kd = min((KK) + 3, _lim);                \
    unsigned _ra = recs[_ka], _rb = recs[_kb];                               \
    unsigned _rc = recs[_kc], _rd = recs[_kd];                               \
    float _ta = (float)(_ra & 32767u) * (1.0f / 16.0f);                      \
    float _tb = (float)(_rb & 32767u) * (1.0f / 16.0f);                      \
    float _tc = (float)(_rc & 32767u) * (1.0f / 16.0f);                      \
    float _td = (float)(_rd & 32767u) * (1.0f / 16.0f);                      \
    int _ia = (int)_ta, _ib = (int)_tb, _ic = (int)_tc, _id = (int)_td;      \
    float _fa = s_lut[_ia], _fb = s_lut[_ib];                                \
    float _fc = s_lut[_ic], _fd = s_lut[_id];                                \
    float _va = _fa + (_ta - (float)_ia) * (s_lut[_ia + 1] - _fa);           \
    float _vb = _fb + (_tb - (float)_ib) * (s_lut[_ib + 1] - _fb);           \
    float _vc = _fc + (_tc - (float)_ic) * (s_lut[_ic + 1] - _fc);           \
    float _vd = _fd + (_td - (float)_id) * (s_lut[_id + 1] - _fd);           \
    _va = ((KK)     < (TT)) ? _va : 0.f;                                     \
    _vb = ((KK) + 1 < (TT)) ? _vb : 0.f;                                     \
    _vc = ((KK) + 2 < (TT)) ? _vc : 0.f;                                     \
    _vd = ((KK) + 3 < (TT)) ? _vd : 0.f;                                     \
    union { uint4 u; h2 v[4]; } _pa, _pb, _pc, _pd;                          \
    _pa.u = h4[(_ra >> 15) * 8u + (unsigned)ci];                             \
    _pb.u = h4[(_rb >> 15) * 8u + (unsigned)ci];                             \
    _pc.u = h4[(_rc >> 15) * 8u + (unsigned)ci];                             \
    _pd.u = h4[(_rd >> 15) * 8u + (unsigned)ci];                             \
    _Float16 _ha = (_Float16)_va, _hb = (_Float16)_vb;                       \
    _Float16 _hc = (_Float16)_vc, _hd = (_Float16)_vd;                       \
    h2 _aa = (h2){_ha, _ha}, _ab = (h2){_hb, _hb};                           \
    h2 _ac = (h2){_hc, _hc}, _ad = (h2){_hd, _hd};                           \
    _Pragma("unroll")                                                        \
    for (int _q = 0; _q < 4; _q++) (ACC)[_q] += _aa * _pa.v[_q];             \
    _Pragma("unroll")                                                        \
    for (int _q = 0; _q < 4; _q++) (ACC)[_q] += _ab * _pb.v[_q];             \
    _Pragma("unroll")                                                        \
    for (int _q = 0; _q < 4; _q++) (ACC)[_q] += _ac * _pc.v[_q];             \
    _Pragma("unroll")                                                        \
    for (int _q = 0; _q < 4; _q++) (ACC)[_q] += _ad * _pd.v[_q];             \
} while (0)

// Fused layer. Phase A: group-owns-TWO-rows interleaved — 8 groups x 8 lanes;
// each group walks BOTH its rows with 4-edge unroll each (8 independent
// rec->gather chains in flight per group). Phase B: 64x64x2 MLP as 16 MFMAs.
// last=1: skip h store, emit per-wave 64-channel partial sums for the mean.
__global__ __launch_bounds__(256, 6)
void k_layer(const int* __restrict__ row_ptr, const unsigned int* __restrict__ recs,
             const float* __restrict__ lutl, const h8* __restrict__ Wsw,
             const float* __restrict__ b1, const float* __restrict__ b2p,
             const _Float16* __restrict__ h_in, _Float16* __restrict__ h_out,
             float* __restrict__ pA, int N, int last) {
    __shared__ float s_lut[LUTN + 1];       // 8196 B
    __shared__ _Float16 sA[64 * ASTRIDE];   // 9216 B
    for (int i = threadIdx.x; i <= LUTN; i += 256) s_lut[i] = lutl[i];
    __syncthreads();

    int lane = threadIdx.x & 63;
    int w = threadIdx.x >> 6;
    int base = blockIdx.x * 64 + w * 16;    // this wave's 16 nodes
    int g = lane >> 3, ci = lane & 7;       // 8 groups x 8 lanes
    const uint4* h4 = (const uint4*)h_in;   // 8 halves per uint4; 8 per row

    // ---- phase A: two rows per group, interleaved ----
    {
        int node0 = base + g;
        int node1 = base + 8 + g;
        h2 acc0[4], acc1[4];
#pragma unroll
        for (int q = 0; q < 4; q++) {
            acc0[q] = (h2){(_Float16)0.f, (_Float16)0.f};
            acc1[q] = (h2){(_Float16)0.f, (_Float16)0.f};
        }
        int s0 = 0, t0 = 0, s1 = 0, t1 = 0;
        if (node0 < N) { s0 = row_ptr[node0]; t0 = row_ptr[node0 + 1]; }
        if (node1 < N) { s1 = row_ptr[node1]; t1 = row_ptr[node1 + 1]; }
        int it0 = (t0 - s0 + 3) >> 2;
        int it1 = (t1 - s1 + 3) >> 2;
        int iters = max(it0, it1);
        for (int it = 0; it < iters; ++it) {
            int k0 = s0 + it * 4;
            int k1 = s1 + it * 4;
            PROC4(k0, s0, t0, acc0);
            PROC4(k1, s1, t1, acc1);
        }
        union { uint4 u4; h2 v[4]; } pk;
#pragma unroll
        for (int q = 0; q < 4; q++) pk.v[q] = acc0[q];
        *(uint4*)&sA[(size_t)(w * 16 + g) * ASTRIDE + ci * 8] = pk.u4;
#pragma unroll
        for (int q = 0; q < 4; q++) pk.v[q] = acc1[q];
        *(uint4*)&sA[(size_t)(w * 16 + 8 + g) * ASTRIDE + ci * 8] = pk.u4;
    }
    // wave-private LDS rows: in-wave ds ordering, no barrier needed

    // ---- phase B: MFMA MLP ----
    int q4 = lane >> 4, c16 = lane & 15;
    int rowb = w * 16;
    const h8* WB1 = Wsw;            // frags [kt][nt][lane]
    const h8* WB2 = Wsw + 8 * 64;
    h8 A0 = *(const h8*)&sA[(size_t)(rowb + c16) * ASTRIDE + q4 * 8];
    h8 A1 = *(const h8*)&sA[(size_t)(rowb + c16) * ASTRIDE + 32 + q4 * 8];
    f32x4 C1[4];
#pragma unroll
    for (int nt = 0; nt < 4; nt++) {
        f32x4 c = {0.f, 0.f, 0.f, 0.f};
        c = __builtin_amdgcn_mfma_f32_16x16x32_f16(A0, WB1[nt * 64 + lane], c, 0, 0, 0);
        c = __builtin_amdgcn_mfma_f32_16x16x32_f16(A1, WB1[(4 + nt) * 64 + lane], c, 0, 0, 0);
        C1[nt] = c;
    }
#pragma unroll
    for (int nt = 0; nt < 4; nt++) {
        float bb = b1[nt * 16 + c16];
#pragma unroll
        for (int reg = 0; reg < 4; reg++) {
            float v = softplus_f(C1[nt][reg] + bb);
            sA[(size_t)(rowb + q4 * 4 + reg) * ASTRIDE + nt * 16 + c16] = (_Float16)v;
        }
    }
    h8 M0 = *(const h8*)&sA[(size_t)(rowb + c16) * ASTRIDE + q4 * 8];
    h8 M1 = *(const h8*)&sA[(size_t)(rowb + c16) * ASTRIDE + 32 + q4 * 8];
    f32x4 C2[4];
#pragma unroll
    for (int nt = 0; nt < 4; nt++) {
        f32x4 c = {0.f, 0.f, 0.f, 0.f};
        c = __builtin_amdgcn_mfma_f32_16x16x32_f16(M0, WB2[nt * 64 + lane], c, 0, 0, 0);
        c = __builtin_amdgcn_mfma_f32_16x16x32_f16(M1, WB2[(4 + nt) * 64 + lane], c, 0, 0, 0);
        C2[nt] = c;
    }
    // epilogue: + b2' (BN folded), fp16 residual
    if (!last) {
#pragma unroll
        for (int nt = 0; nt < 4; nt++) {
            float bb2 = b2p[nt * 16 + c16];
#pragma unroll
            for (int reg = 0; reg < 4; reg++) {
                int node = base + q4 * 4 + reg;
                if (node < N) {
                    size_t idx = (size_t)node * H + nt * 16 + c16;
                    float hn = (float)h_in[idx] + C2[nt][reg] + bb2;
                    h_out[idx] = (_Float16)hn;
                }
            }
        }
    } else {
        // last layer: per-wave column partial sums (no h store)
        float ps[4];
#pragma unroll
        for (int nt = 0; nt < 4; nt++) {
            float bb2 = b2p[nt * 16 + c16];
            float s = 0.f;
#pragma unroll
            for (int reg = 0; reg < 4; reg++) {
                int node = base + q4 * 4 + reg;
                if (node < N) {
                    size_t idx = (size_t)node * H + nt * 16 + c16;
                    s += (float)h_in[idx] + C2[nt][reg] + bb2;
                }
            }
            ps[nt] = s;
        }
#pragma unroll
        for (int nt = 0; nt < 4; nt++) {
            float v = ps[nt];
            v += __shfl_xor(v, 16, 64);
            v += __shfl_xor(v, 32, 64);
            if (lane < 16)
                pA[((size_t)blockIdx.x * 4 + w) * H + nt * 16 + c16] = v;
        }
    }
}

// Stage 1 of mean: reduce per-wave partials (P rows) to MEANB rows.
__global__ __launch_bounds__(256)
void k_mean(const float* __restrict__ pA, float* __restrict__ partials, int P) {
    __shared__ float s_r[4][H];
    int lane = threadIdx.x & 63;
    int w = threadIdx.x >> 6;
    int wg = blockIdx.x * 4 + w;
    int stride = gridDim.x * 4;
    float local = 0.f;
    for (int i = wg; i < P; i += stride) local += pA[(size_t)i * H + lane];
    s_r[w][lane] = local;
    __syncthreads();
    if (w == 0) {
        float s = s_r[0][lane] + s_r[1][lane] + s_r[2][lane] + s_r[3][lane];
        partials[(size_t)blockIdx.x * H + lane] = s;
    }
}

// Stage 2: one block reduces MEANB partial rows, then the tiny output MLP.
__global__ __launch_bounds__(256)
void k_final(const float* __restrict__ partials, int N,
             const float* __restrict__ oW1, const float* __restrict__ ob1,
             const float* __restrict__ og1, const float* __restrict__ obt1,
             const float* __restrict__ oW2, const float* __restrict__ ob2,
             const float* __restrict__ og2, const float* __restrict__ obt2,
             const float* __restrict__ fin_W, const float* __restrict__ fin_b,
             float* __restrict__ out) {
    __shared__ float red[4][H];
    __shared__ float sg[H], su[H / 2], sv[H / 2];
    int t = threadIdx.x;
    int ch = t & 63, grp = t >> 6;
    float s = 0.f;
    for (int b = grp; b < MEANB; b += 4) s += partials[(size_t)b * H + ch];
    red[grp][ch] = s;
    __syncthreads();
    if (t < H) sg[t] = (red[0][t] + red[1][t] + red[2][t] + red[3][t]) / (float)N;
    __syncthreads();
    int j = t;
    if (j < H / 2) {
        float acc = ob1[j];
        for (int k = 0; k < H; k++) acc += sg[k] * oW1[k * (H / 2) + j];
        su[j] = softplus_f(acc) * BN_INV * og1[j] + obt1[j];
    }
    __syncthreads();
    if (j < H / 2) {
        float acc = ob2[j];
        for (int k = 0; k < H / 2; k++) acc += su[k] * oW2[k * (H / 2) + j];
        sv[j] = softplus_f(acc) * BN_INV * og2[j] + obt2[j];
    }
    __syncthreads();
    if (j < 3) {
        float acc = fin_b[j];
        for (int k = 0; k < H / 2; k++) acc += sv[k] * fin_W[k * 3 + j];
        out[j] = acc;
    }
}

extern "C" void kernel_launch(void* const* d_in, const int* in_sizes, int n_in,
                              void* d_out, int out_size, void* d_ws, size_t ws_size,
                              hipStream_t stream) {
    const float* x      = (const float*)d_in[0];
    const int*   ei     = (const int*)d_in[1];
    const float* dist   = (const float*)d_in[2];
    /* d_in[3] edge_attr: unused by reference */
    const float* emb_W  = (const float*)d_in[4];
    const float* emb_b  = (const float*)d_in[5];
    const float* fW1    = (const float*)d_in[6];
    const float* fb1    = (const float*)d_in[7];
    const float* fW2    = (const float*)d_in[8];
    const float* fb2    = (const float*)d_in[9];
    const float* iW1    = (const float*)d_in[10];
    const float* ib1    = (const float*)d_in[11];
    const float* iW2    = (const float*)d_in[12];
    const float* ib2    = (const float*)d_in[13];
    const float* bn_g   = (const float*)d_in[14];
    const float* bn_b   = (const float*)d_in[15];
    const float* oW1    = (const float*)d_in[16];
    const float* ob1    = (const float*)d_in[17];
    const float* og1    = (const float*)d_in[18];
    const float* obt1   = (const float*)d_in[19];
    const float* oW2    = (const float*)d_in[20];
    const float* ob2    = (const float*)d_in[21];
    const float* og2    = (const float*)d_in[22];
    const float* obt2   = (const float*)d_in[23];
    const float* fin_W  = (const float*)d_in[24];
    const float* fin_b  = (const float*)d_in[25];
    float* out = (float*)d_out;

    int N = in_sizes[0] / FIN;
    int E = in_sizes[2];
    int NB = (N + BROWS - 1) / BROWS;          // sort buckets (391 @ N=100k)
    int nb_tile = (N + 63) / 64;
    int P = nb_tile * 4;                       // per-wave partial rows

    // workspace layout (16B-aligned chunks first)
    float*  ws   = (float*)d_ws;
    _Float16* h0 = (_Float16*)ws;                          // N*H fp16
    _Float16* h1 = h0 + (size_t)N * H;                     // N*H fp16
    unsigned int* recs = (unsigned int*)(h1 + (size_t)N * H);    // E uint32
    h8*     Wsw  = (h8*)(recs + E);                        // 3*2*8*64 h8
    float*  lut  = (float*)(Wsw + NLAYERS * 2 * 8 * 64);   // 3*LUTSTRIDE
    float*  partials = lut + 3 * LUTSTRIDE;                // MEANB*H
    float*  b2p  = partials + MEANB * H;                   // L*H
    float*  pA   = b2p + NLAYERS * H;                      // P*H
    u32x2*  stg  = (u32x2*)(pA + (size_t)P * H);           // NBMAX*MAXC u32x2
    int*    row_ptr = (int*)(stg + (size_t)NBMAX * MAXC);  // N+1
    unsigned int* cursor = (unsigned int*)(row_ptr + N + 1);     // NBMAX

    hipMemsetAsync(cursor, 0, NBMAX * sizeof(unsigned int), stream);

    int nbA = (E + ABLK - 1) / ABLK;
    int nb_pre = nbA + NLAYERS * 3 + 3;
    k_pre<<<nb_pre, 1024, 0, stream>>>(fW1, fb1, fW2, fb2, iW1, iW2,
                                       bn_g, bn_b, ib2, Wsw, b2p, lut,
                                       ei, dist, cursor, stg,
                                       N, E, NB, nbA);

    k_passB<<<NB, 1024, 0, stream>>>(stg, cursor, row_ptr, recs,
                                     x, emb_W, emb_b, h0, N, NB);

    _Float16* hp[2] = {h0, h1};
    for (int l = 0; l < NLAYERS; l++) {
        k_layer<<<nb_tile, 256, 0, stream>>>(row_ptr, recs, lut + (size_t)l * LUTSTRIDE,
                                             Wsw + (size_t)l * 1024,
                                             ib1 + l * H, b2p + l * H,
                                             hp[l & 1], hp[(l + 1) & 1], pA, N,
                                             (l == NLAYERS - 1) ? 1 : 0);
    }

    k_mean<<<MEANB, 256, 0, stream>>>(pA, partials, P);
    k_final<<<1, 256, 0, stream>>>(partials, N, oW1, ob1, og1, obt1,
                                   oW2, ob2, og2, obt2, fin_W, fin_b, out);
}

// Round 14
// 323.536 us; speedup vs baseline: 1.0366x; 1.0366x over previous
//
#include <hip/hip_runtime.h>
#include <hip/hip_fp16.h>
#include <math.h>

#define CUTOFF 5.0f
#define H 64
#define FIN 16
#define NLAYERS 3
#define LUTN 2048          // intervals; table has LUTN+1 entries
#define LUTSTRIDE 2052     // padded per-layer stride
#define ASTRIDE 72         // LDS row stride in halves (144B, 16B-aligned)
#define MEANB 256          // blocks in mean pass (partials rows)
#define BROWS 256          // rows per sort bucket
#define NBMAX 512          // max buckets (N <= 128K)
#define MAXC 5120          // per-bucket stg stride AND LDS sort capacity (20KB)
#define ABLK 4096          // edges per pass-A block
#define NREP 4             // counter replicas (wave-groups) to cut atomic depth

// 1/sqrt(1 + 1e-3)  (BN inference, moving mean 0 / var 1)
#define BN_INV 0.999500374750f

typedef _Float16 h8 __attribute__((ext_vector_type(8)));
typedef _Float16 h2 __attribute__((ext_vector_type(2)));
typedef float f32x4 __attribute__((ext_vector_type(4)));
typedef unsigned int u32x2 __attribute__((ext_vector_type(2)));

__device__ __forceinline__ float softplus_f(float x) {
    return fmaxf(x, 0.f) + __logf(1.f + __expf(-fabsf(x)));
}

// ---- K_pre: fused passA + embed + setup. Block roles:
//   [0, nbA)             passA: 1-atomic/record bucket sort (replicated cnt)
//   [nbA, +nbE16)        embed 16 nodes/block -> h0 fp16
//   [.., +9)             LUT: inline wsum/bsum, 1024 entries/block
//   [.., +3)             weight swizzle Wsw + b2p
__global__ __launch_bounds__(1024)
void k_pre(const float* __restrict__ x, const float* __restrict__ emb_W,
           const float* __restrict__ emb_b, _Float16* __restrict__ h0,
           const float* __restrict__ fW1, const float* __restrict__ fb1,
           const float* __restrict__ fW2, const float* __restrict__ fb2,
           const float* __restrict__ iW1, const float* __restrict__ iW2,
           const float* __restrict__ bn_g, const float* __restrict__ bn_b,
           const float* __restrict__ ib2, h8* __restrict__ Wsw,
           float* __restrict__ b2p, float* __restrict__ lut,
           const int* __restrict__ ei, const float* __restrict__ dist,
           unsigned int* __restrict__ cursor, u32x2* __restrict__ stg,
           int N, int E, int NB, int nbA, int nbE16) {
    __shared__ u32x2 s_rec[ABLK];              // 32KB block-local sorted records
    __shared__ unsigned s_cnt[NBMAX * NREP];   // 8KB replicated counts
    __shared__ unsigned s_tot[NBMAX];          // scan -> bucket lstart
    __shared__ unsigned s_gst[NBMAX * NREP];   // per-(bucket,group) local starts
    __shared__ unsigned s_gbase[NBMAX];        // global bases (cursor-reserved)
    __shared__ float swsum[64];
    __shared__ float sbsum;
    int b = blockIdx.x;
    int t = threadIdx.x;
    if (b < nbA) {
        // ---- passA role ----
        int e0 = b * ABLK;
        int nE = min(ABLK, E - e0);
        int gg = t >> 8;                       // wave-group 0..3
        for (int i = t; i < NBMAX * NREP; i += 1024) s_cnt[i] = 0;
        __syncthreads();
        int rowv[4];
        unsigned rxv[4] = {0u, 0u, 0u, 0u};
        unsigned rkv[4] = {0u, 0u, 0u, 0u};
#pragma unroll
        for (int j = 0; j < 4; j++) {
            int li = j * 1024 + t;
            rowv[j] = -1;
            if (li < nE) {
                int e = e0 + li;
                int r = ei[e];
                int col = ei[E + e];
                float d = dist[e];
                int didx = (int)(d * (32768.0f / CUTOFF) + 0.5f);
                didx = max(0, min(didx, 32767));
                rowv[j] = r;
                rxv[j] = ((unsigned)col << 15) | (unsigned)didx;
                rkv[j] = atomicAdd(&s_cnt[(r / BROWS) * NREP + gg], 1u);
            }
        }
        __syncthreads();
        unsigned tot = 0;
        if (t < NBMAX) {
            tot = s_cnt[t * NREP] + s_cnt[t * NREP + 1] +
                  s_cnt[t * NREP + 2] + s_cnt[t * NREP + 3];
            s_tot[t] = tot;
        }
        __syncthreads();
        for (int off = 1; off < NBMAX; off <<= 1) {
            unsigned v = 0;
            if (t < NBMAX && t >= off) v = s_tot[t - off];
            __syncthreads();
            if (t < NBMAX) s_tot[t] += v;
            __syncthreads();
        }
        if (t < NBMAX) {
            unsigned lstart = s_tot[t] - tot;
            unsigned runb = lstart;
#pragma unroll
            for (int g = 0; g < NREP; g++) {
                s_gst[t * NREP + g] = runb;
                runb += s_cnt[t * NREP + g];
            }
            s_tot[t] = lstart;                 // repurpose as lstart
            s_gbase[t] = (tot && t < (unsigned)NB) ? atomicAdd(&cursor[t], tot) : 0u;
        }
        __syncthreads();
        // place from rank (NO atomic)
#pragma unroll
        for (int j = 0; j < 4; j++) {
            if (rowv[j] >= 0) {
                int bk = rowv[j] / BROWS;
                unsigned slot = s_gst[bk * NREP + gg] + rkv[j];
                u32x2 rec;
                rec.x = rxv[j];
                rec.y = (unsigned)rowv[j];
                s_rec[slot] = rec;
            }
        }
        __syncthreads();
        // linear walk of sorted records -> per-bucket contiguous global runs
        for (int i = t; i < nE; i += 1024) {
            u32x2 rec = s_rec[i];
            int bk = (int)(rec.y / BROWS);
            unsigned g = s_gbase[bk] + ((unsigned)i - s_tot[bk]);
            if (g < MAXC)                      // overflow guard (~never)
                stg[(size_t)bk * MAXC + g] = rec;
        }
    } else if (b < nbA + nbE16) {
        // ---- embed role: 16 nodes/block ----
        int lane = t & 63;
        int w = t >> 6;
        int node = (b - nbA) * 16 + w;
        if (node < N) {
            float acc = emb_b[lane];
#pragma unroll
            for (int k = 0; k < FIN; k++) acc += x[node * FIN + k] * emb_W[k * H + lane];
            h0[(size_t)node * H + lane] = (_Float16)acc;
        }
    } else if (b < nbA + nbE16 + NLAYERS * 3) {
        // ---- LUT role ----
        int lb = b - nbA - nbE16;
        int l = lb / 3, part = lb % 3;
        if (t < 64) {
            float s = 0.f;
            for (int j = 0; j < H; j++) s += fW2[l * H * H + t * H + j];
            swsum[t] = s;
        }
        if (t == 64) {
            float s = 0.f;
            for (int j = 0; j < H; j++) s += fb2[l * H + j];
            sbsum = s;
        }
        __syncthreads();
        int i = part * 1024 + t;
        if (i <= LUTN) {
            float d = (float)i * (CUTOFF / (float)LUTN);
            float scaled = d * (2.0f / CUTOFF) - 1.0f;
            float cut = 0.5f * (__cosf(d * (3.14159265358979f / CUTOFF)) + 1.0f);
            if (d > CUTOFF) cut = 0.f;
            float s = 0.f;
            for (int hh = 0; hh < H; hh++) {
                int wi = l * H + hh;
                s += tanhf(scaled * fW1[wi] + fb1[wi]) * swsum[hh];
            }
            lut[l * LUTSTRIDE + i] = cut * (s + sbsum);
        }
    } else {
        // ---- weight swizzle role ----
        int tid = (b - nbA - nbE16 - NLAYERS * 3) * 1024 + t;
        if (tid < NLAYERS * H)
            b2p[tid] = ib2[tid] * BN_INV * bn_g[tid] + bn_b[tid];
        if (tid < NLAYERS * 2 * 8 * 64) {
            int lane = tid & 63;
            int frag = (tid >> 6) & 7;
            int mat  = (tid >> 9) & 1;
            int l    = tid >> 10;
            int kt = frag >> 2, nt = frag & 3;
            int n = nt * 16 + (lane & 15);
            int k0 = kt * 32 + (lane >> 4) * 8;
            const float* W = (mat ? iW2 : iW1) + l * H * H;
            float scale = mat ? BN_INV * bn_g[l * H + n] : 1.0f;
            h8 v;
#pragma unroll
            for (int j = 0; j < 8; j++) v[j] = (_Float16)(W[(k0 + j) * H + n] * scale);
            Wsw[tid] = v;
        }
    }
}

// Pass B: per-bucket counting sort + row_ptr. ONE atomic per record
// (replicated per-(row,group) counters; rank+scan placement, no 2nd atomic).
__global__ __launch_bounds__(1024)
void k_passB(const u32x2* __restrict__ stg, const unsigned int* __restrict__ cursor,
             int* __restrict__ row_ptr, unsigned int* __restrict__ recs,
             int N, int NB) {
    __shared__ int s_bb[NBMAX];
    __shared__ unsigned s_c[BROWS * NREP];     // 4KB replicated counts
    __shared__ unsigned s_t[BROWS];
    __shared__ unsigned s_g[BROWS * NREP];     // per-(row,group) starts
    __shared__ unsigned s_out[MAXC];           // 20KB
    int b = blockIdx.x, t = threadIdx.x;
    int gg = t >> 8;
    // bucket counts + redundant inclusive scan over NBMAX
    if (t < NBMAX) {
        int cb = 0;
        if (t < NB) cb = min((int)cursor[t], MAXC);
        s_bb[t] = cb;
    }
    __syncthreads();
    for (int off = 1; off < NBMAX; off <<= 1) {
        int v = 0;
        if (t < NBMAX && t >= off) v = s_bb[t - off];
        __syncthreads();
        if (t < NBMAX) s_bb[t] += v;
        __syncthreads();
    }
    int bbase = (b > 0) ? s_bb[b - 1] : 0;
    int cnt = s_bb[b] - bbase;
    int r0 = b * BROWS;
    int r1 = min(r0 + BROWS, N);
    int nrows = r1 - r0;
    const u32x2* mystg = stg + (size_t)b * MAXC;
    for (int i = t; i < BROWS * NREP; i += 1024) s_c[i] = 0;
    __syncthreads();
    // single stg read: count + remember record & rank (static-index regs)
    u32x2 myrec[5];
    unsigned myrk[5] = {0u, 0u, 0u, 0u, 0u};
    int nm = 0;
#pragma unroll
    for (int i = 0; i < 5; i++) {
        int idx = t + i * 1024;
        if (idx < cnt) {
            myrec[i] = mystg[idx];
            myrk[i] = atomicAdd(&s_c[((int)myrec[i].y - r0) * NREP + gg], 1u);
            nm = i + 1;
        }
    }
    __syncthreads();
    unsigned tot = 0;
    if (t < BROWS) {
        tot = s_c[t * NREP] + s_c[t * NREP + 1] +
              s_c[t * NREP + 2] + s_c[t * NREP + 3];
        s_t[t] = tot;
    }
    __syncthreads();
    for (int off = 1; off < BROWS; off <<= 1) {
        unsigned v = 0;
        if (t < BROWS && t >= off) v = s_t[t - off];
        __syncthreads();
        if (t < BROWS) s_t[t] += v;
        __syncthreads();
    }
    if (t < BROWS) {
        unsigned excl = s_t[t] - tot;
        if (t < nrows) row_ptr[r0 + t] = bbase + (int)excl;
        unsigned runb = excl;
#pragma unroll
        for (int g = 0; g < NREP; g++) {
            s_g[t * NREP + g] = runb;
            runb += s_c[t * NREP + g];
        }
    }
    if (b == NB - 1 && t == 0) row_ptr[N] = bbase + cnt;
    __syncthreads();
    // place from rank (NO atomic)
#pragma unroll
    for (int i = 0; i < 5; i++)
        if (i < nm) {
            unsigned slot = s_g[((int)myrec[i].y - r0) * NREP + gg] + myrk[i];
            s_out[slot] = myrec[i].x;
        }
    __syncthreads();
    for (int i = t; i < cnt; i += 1024)
        recs[bbase + i] = s_out[i];
}

// 4-edge clamped processing for one row: loads recs+h, lerps fv, accumulates.
#define PROC4(KK, SS, TT, ACC) do {                                          \
    int _lim = ((TT) > (SS)) ? (TT) - 1 : 0;                                 \
    int _ka = min((KK), _lim),     _kb = min((KK) + 1, _lim);                \
    int _kc = min((KK) + 2, _lim), _kd = min((KK) + 3, _lim);                \
    unsigned _ra = recs[_ka], _rb = recs[_kb];                               \
    unsigned _rc = recs[_kc], _rd = recs[_kd];                               \
    float _ta = (float)(_ra & 32767u) * (1.0f / 16.0f);                      \
    float _tb = (float)(_rb & 32767u) * (1.0f / 16.0f);                      \
    float _tc = (float)(_rc & 32767u) * (1.0f / 16.0f);                      \
    float _td = (float)(_rd & 32767u) * (1.0f / 16.0f);                      \
    int _ia = (int)_ta, _ib = (int)_tb, _ic = (int)_tc, _id = (int)_td;      \
    float _fa = s_lut[_ia], _fb = s_lut[_ib];                                \
    float _fc = s_lut[_ic], _fd = s_lut[_id];                                \
    float _va = _fa + (_ta - (float)_ia) * (s_lut[_ia + 1] - _fa);           \
    float _vb = _fb + (_tb - (float)_ib) * (s_lut[_ib + 1] - _fb);           \
    float _vc = _fc + (_tc - (float)_ic) * (s_lut[_ic + 1] - _fc);           \
    float _vd = _fd + (_td - (float)_id) * (s_lut[_id + 1] - _fd);           \
    _va = ((KK)     < (TT)) ? _va : 0.f;                                     \
    _vb = ((KK) + 1 < (TT)) ? _vb : 0.f;                                     \
    _vc = ((KK) + 2 < (TT)) ? _vc : 0.f;                                     \
    _vd = ((KK) + 3 < (TT)) ? _vd : 0.f;                                     \
    union { uint4 u; h2 v[4]; } _pa, _pb, _pc, _pd;                          \
    _pa.u = h4[(_ra >> 15) * 8u + (unsigned)ci];                             \
    _pb.u = h4[(_rb >> 15) * 8u + (unsigned)ci];                             \
    _pc.u = h4[(_rc >> 15) * 8u + (unsigned)ci];                             \
    _pd.u = h4[(_rd >> 15) * 8u + (unsigned)ci];                             \
    _Float16 _ha = (_Float16)_va, _hb = (_Float16)_vb;                       \
    _Float16 _hc = (_Float16)_vc, _hd = (_Float16)_vd;                       \
    h2 _aa = (h2){_ha, _ha}, _ab = (h2){_hb, _hb};                           \
    h2 _ac = (h2){_hc, _hc}, _ad = (h2){_hd, _hd};                           \
    _Pragma("unroll")                                                        \
    for (int _q = 0; _q < 4; _q++) (ACC)[_q] += _aa * _pa.v[_q];             \
    _Pragma("unroll")                                                        \
    for (int _q = 0; _q < 4; _q++) (ACC)[_q] += _ab * _pb.v[_q];             \
    _Pragma("unroll")                                                        \
    for (int _q = 0; _q < 4; _q++) (ACC)[_q] += _ac * _pc.v[_q];             \
    _Pragma("unroll")                                                        \
    for (int _q = 0; _q < 4; _q++) (ACC)[_q] += _ad * _pd.v[_q];             \
} while (0)

// Fused layer. Phase A: group-owns-TWO-rows interleaved — 8 groups x 8 lanes;
// each group walks BOTH its rows with 4-edge unroll each (8 independent
// rec->gather chains in flight per group). Phase B: 64x64x2 MLP as 16 MFMAs.
// last=1: skip h store, emit per-wave 64-channel partial sums for the mean.
__global__ __launch_bounds__(256, 6)
void k_layer(const int* __restrict__ row_ptr, const unsigned int* __restrict__ recs,
             const float* __restrict__ lutl, const h8* __restrict__ Wsw,
             const float* __restrict__ b1, const float* __restrict__ b2p,
             const _Float16* __restrict__ h_in, _Float16* __restrict__ h_out,
             float* __restrict__ pA, int N, int last) {
    __shared__ float s_lut[LUTN + 1];       // 8196 B
    __shared__ _Float16 sA[64 * ASTRIDE];   // 9216 B
    for (int i = threadIdx.x; i <= LUTN; i += 256) s_lut[i] = lutl[i];
    __syncthreads();

    int lane = threadIdx.x & 63;
    int w = threadIdx.x >> 6;
    int base = blockIdx.x * 64 + w * 16;    // this wave's 16 nodes
    int g = lane >> 3, ci = lane & 7;       // 8 groups x 8 lanes
    const uint4* h4 = (const uint4*)h_in;   // 8 halves per uint4; 8 per row

    // ---- phase A: two rows per group, interleaved ----
    {
        int node0 = base + g;
        int node1 = base + 8 + g;
        h2 acc0[4], acc1[4];
#pragma unroll
        for (int q = 0; q < 4; q++) {
            acc0[q] = (h2){(_Float16)0.f, (_Float16)0.f};
            acc1[q] = (h2){(_Float16)0.f, (_Float16)0.f};
        }
        int s0 = 0, t0 = 0, s1 = 0, t1 = 0;
        if (node0 < N) { s0 = row_ptr[node0]; t0 = row_ptr[node0 + 1]; }
        if (node1 < N) { s1 = row_ptr[node1]; t1 = row_ptr[node1 + 1]; }
        int it0 = (t0 - s0 + 3) >> 2;
        int it1 = (t1 - s1 + 3) >> 2;
        int iters = max(it0, it1);
        for (int it = 0; it < iters; ++it) {
            int k0 = s0 + it * 4;
            int k1 = s1 + it * 4;
            PROC4(k0, s0, t0, acc0);
            PROC4(k1, s1, t1, acc1);
        }
        union { uint4 u4; h2 v[4]; } pk;
#pragma unroll
        for (int q = 0; q < 4; q++) pk.v[q] = acc0[q];
        *(uint4*)&sA[(size_t)(w * 16 + g) * ASTRIDE + ci * 8] = pk.u4;
#pragma unroll
        for (int q = 0; q < 4; q++) pk.v[q] = acc1[q];
        *(uint4*)&sA[(size_t)(w * 16 + 8 + g) * ASTRIDE + ci * 8] = pk.u4;
    }
    // wave-private LDS rows: in-wave ds ordering, no barrier needed

    // ---- phase B: MFMA MLP ----
    int q4 = lane >> 4, c16 = lane & 15;
    int rowb = w * 16;
    const h8* WB1 = Wsw;            // frags [kt][nt][lane]
    const h8* WB2 = Wsw + 8 * 64;
    h8 A0 = *(const h8*)&sA[(size_t)(rowb + c16) * ASTRIDE + q4 * 8];
    h8 A1 = *(const h8*)&sA[(size_t)(rowb + c16) * ASTRIDE + 32 + q4 * 8];
    f32x4 C1[4];
#pragma unroll
    for (int nt = 0; nt < 4; nt++) {
        f32x4 c = {0.f, 0.f, 0.f, 0.f};
        c = __builtin_amdgcn_mfma_f32_16x16x32_f16(A0, WB1[nt * 64 + lane], c, 0, 0, 0);
        c = __builtin_amdgcn_mfma_f32_16x16x32_f16(A1, WB1[(4 + nt) * 64 + lane], c, 0, 0, 0);
        C1[nt] = c;
    }
#pragma unroll
    for (int nt = 0; nt < 4; nt++) {
        float bb = b1[nt * 16 + c16];
#pragma unroll
        for (int reg = 0; reg < 4; reg++) {
            float v = softplus_f(C1[nt][reg] + bb);
            sA[(size_t)(rowb + q4 * 4 + reg) * ASTRIDE + nt * 16 + c16] = (_Float16)v;
        }
    }
    h8 M0 = *(const h8*)&sA[(size_t)(rowb + c16) * ASTRIDE + q4 * 8];
    h8 M1 = *(const h8*)&sA[(size_t)(rowb + c16) * ASTRIDE + 32 + q4 * 8];
    f32x4 C2[4];
#pragma unroll
    for (int nt = 0; nt < 4; nt++) {
        f32x4 c = {0.f, 0.f, 0.f, 0.f};
        c = __builtin_amdgcn_mfma_f32_16x16x32_f16(M0, WB2[nt * 64 + lane], c, 0, 0, 0);
        c = __builtin_amdgcn_mfma_f32_16x16x32_f16(M1, WB2[(4 + nt) * 64 + lane], c, 0, 0, 0);
        C2[nt] = c;
    }
    // epilogue: + b2' (BN folded), fp16 residual
    if (!last) {
#pragma unroll
        for (int nt = 0; nt < 4; nt++) {
            float bb2 = b2p[nt * 16 + c16];
#pragma unroll
            for (int reg = 0; reg < 4; reg++) {
                int node = base + q4 * 4 + reg;
                if (node < N) {
                    size_t idx = (size_t)node * H + nt * 16 + c16;
                    float hn = (float)h_in[idx] + C2[nt][reg] + bb2;
                    h_out[idx] = (_Float16)hn;
                }
            }
        }
    } else {
        // last layer: per-wave column partial sums (no h store)
        float ps[4];
#pragma unroll
        for (int nt = 0; nt < 4; nt++) {
            float bb2 = b2p[nt * 16 + c16];
            float s = 0.f;
#pragma unroll
            for (int reg = 0; reg < 4; reg++) {
                int node = base + q4 * 4 + reg;
                if (node < N) {
                    size_t idx = (size_t)node * H + nt * 16 + c16;
                    s += (float)h_in[idx] + C2[nt][reg] + bb2;
                }
            }
            ps[nt] = s;
        }
#pragma unroll
        for (int nt = 0; nt < 4; nt++) {
            float v = ps[nt];
            v += __shfl_xor(v, 16, 64);
            v += __shfl_xor(v, 32, 64);
            if (lane < 16)
                pA[((size_t)blockIdx.x * 4 + w) * H + nt * 16 + c16] = v;
        }
    }
}

// Stage 1 of mean: reduce per-wave partials (P rows) to MEANB rows.
__global__ __launch_bounds__(256)
void k_mean(const float* __restrict__ pA, float* __restrict__ partials, int P) {
    __shared__ float s_r[4][H];
    int lane = threadIdx.x & 63;
    int w = threadIdx.x >> 6;
    int wg = blockIdx.x * 4 + w;
    int stride = gridDim.x * 4;
    float local = 0.f;
    for (int i = wg; i < P; i += stride) local += pA[(size_t)i * H + lane];
    s_r[w][lane] = local;
    __syncthreads();
    if (w == 0) {
        float s = s_r[0][lane] + s_r[1][lane] + s_r[2][lane] + s_r[3][lane];
        partials[(size_t)blockIdx.x * H + lane] = s;
    }
}

// Stage 2: one block reduces MEANB partial rows, then the tiny output MLP.
__global__ __launch_bounds__(256)
void k_final(const float* __restrict__ partials, int N,
             const float* __restrict__ oW1, const float* __restrict__ ob1,
             const float* __restrict__ og1, const float* __restrict__ obt1,
             const float* __restrict__ oW2, const float* __restrict__ ob2,
             const float* __restrict__ og2, const float* __restrict__ obt2,
             const float* __restrict__ fin_W, const float* __restrict__ fin_b,
             float* __restrict__ out) {
    __shared__ float red[4][H];
    __shared__ float sg[H], su[H / 2], sv[H / 2];
    int t = threadIdx.x;
    int ch = t & 63, grp = t >> 6;
    float s = 0.f;
    for (int b = grp; b < MEANB; b += 4) s += partials[(size_t)b * H + ch];
    red[grp][ch] = s;
    __syncthreads();
    if (t < H) sg[t] = (red[0][t] + red[1][t] + red[2][t] + red[3][t]) / (float)N;
    __syncthreads();
    int j = t;
    if (j < H / 2) {
        float acc = ob1[j];
        for (int k = 0; k < H; k++) acc += sg[k] * oW1[k * (H / 2) + j];
        su[j] = softplus_f(acc) * BN_INV * og1[j] + obt1[j];
    }
    __syncthreads();
    if (j < H / 2) {
        float acc = ob2[j];
        for (int k = 0; k < H / 2; k++) acc += su[k] * oW2[k * (H / 2) + j];
        sv[j] = softplus_f(acc) * BN_INV * og2[j] + obt2[j];
    }
    __syncthreads();
    if (j < 3) {
        float acc = fin_b[j];
        for (int k = 0; k < H / 2; k++) acc += sv[k] * fin_W[k * 3 + j];
        out[j] = acc;
    }
}

extern "C" void kernel_launch(void* const* d_in, const int* in_sizes, int n_in,
                              void* d_out, int out_size, void* d_ws, size_t ws_size,
                              hipStream_t stream) {
    const float* x      = (const float*)d_in[0];
    const int*   ei     = (const int*)d_in[1];
    const float* dist   = (const float*)d_in[2];
    /* d_in[3] edge_attr: unused by reference */
    const float* emb_W  = (const float*)d_in[4];
    const float* emb_b  = (const float*)d_in[5];
    const float* fW1    = (const float*)d_in[6];
    const float* fb1    = (const float*)d_in[7];
    const float* fW2    = (const float*)d_in[8];
    const float* fb2    = (const float*)d_in[9];
    const float* iW1    = (const float*)d_in[10];
    const float* ib1    = (const float*)d_in[11];
    const float* iW2    = (const float*)d_in[12];
    const float* ib2    = (const float*)d_in[13];
    const float* bn_g   = (const float*)d_in[14];
    const float* bn_b   = (const float*)d_in[15];
    const float* oW1    = (const float*)d_in[16];
    const float* ob1    = (const float*)d_in[17];
    const float* og1    = (const float*)d_in[18];
    const float* obt1   = (const float*)d_in[19];
    const float* oW2    = (const float*)d_in[20];
    const float* ob2    = (const float*)d_in[21];
    const float* og2    = (const float*)d_in[22];
    const float* obt2   = (const float*)d_in[23];
    const float* fin_W  = (const float*)d_in[24];
    const float* fin_b  = (const float*)d_in[25];
    float* out = (float*)d_out;

    int N = in_sizes[0] / FIN;
    int E = in_sizes[2];
    int NB = (N + BROWS - 1) / BROWS;          // sort buckets (391 @ N=100k)
    int nb_tile = (N + 63) / 64;
    int P = nb_tile * 4;                       // per-wave partial rows

    // workspace layout (16B-aligned chunks first)
    float*  ws   = (float*)d_ws;
    _Float16* h0 = (_Float16*)ws;                          // N*H fp16
    _Float16* h1 = h0 + (size_t)N * H;                     // N*H fp16
    unsigned int* recs = (unsigned int*)(h1 + (size_t)N * H);    // E uint32
    h8*     Wsw  = (h8*)(recs + E);                        // 3*2*8*64 h8
    float*  lut  = (float*)(Wsw + NLAYERS * 2 * 8 * 64);   // 3*LUTSTRIDE
    float*  partials = lut + 3 * LUTSTRIDE;                // MEANB*H
    float*  b2p  = partials + MEANB * H;                   // L*H
    float*  pA   = b2p + NLAYERS * H;                      // P*H
    u32x2*  stg  = (u32x2*)(pA + (size_t)P * H);           // NBMAX*MAXC u32x2
    int*    row_ptr = (int*)(stg + (size_t)NBMAX * MAXC);  // N+1
    unsigned int* cursor = (unsigned int*)(row_ptr + N + 1);     // NBMAX

    hipMemsetAsync(cursor, 0, NBMAX * sizeof(unsigned int), stream);

    int nbA = (E + ABLK - 1) / ABLK;
    int nbE16 = (N + 15) / 16;
    int nb_pre = nbA + nbE16 + NLAYERS * 3 + 3;
    k_pre<<<nb_pre, 1024, 0, stream>>>(x, emb_W, emb_b, h0,
                                       fW1, fb1, fW2, fb2, iW1, iW2,
                                       bn_g, bn_b, ib2, Wsw, b2p, lut,
                                       ei, dist, cursor, stg,
                                       N, E, NB, nbA, nbE16);

    k_passB<<<NB, 1024, 0, stream>>>(stg, cursor, row_ptr, recs, N, NB);

    _Float16* hp[2] = {h0, h1};
    for (int l = 0; l < NLAYERS; l++) {
        k_layer<<<nb_tile, 256, 0, stream>>>(row_ptr, recs, lut + (size_t)l * LUTSTRIDE,
                                             Wsw + (size_t)l * 1024,
                                             ib1 + l * H, b2p + l * H,
                                             hp[l & 1], hp[(l + 1) & 1], pA, N,
                                             (l == NLAYERS - 1) ? 1 : 0);
    }

    k_mean<<<MEANB, 256, 0, stream>>>(pA, partials, P);
    k_final<<<1, 256, 0, stream>>>(partials, N, oW1, ob1, og1, obt1,
                                   oW2, ob2, og2, obt2, fin_W, fin_b, out);
}

// Round 17
// 299.489 us; speedup vs baseline: 1.1198x; 1.0803x over previous
//
#include <hip/hip_runtime.h>
#include <hip/hip_fp16.h>
#include <math.h>

#define CUTOFF 5.0f
#define H 64
#define FIN 16
#define NLAYERS 3
#define LUTN 2048          // intervals; table has LUTN+1 entries
#define LUTSTRIDE 2052     // padded per-layer stride
#define ASTRIDE 72         // LDS row stride in halves (144B, 16B-aligned)
#define MEANB 256          // blocks in mean pass (partials rows)
#define BROWS 256          // rows per sort bucket
#define NBMAX 512          // max buckets (N <= 128K)
#define MAXC 5120          // per-bucket stg stride AND LDS sort capacity (20KB)
#define ABLK 4096          // edges per pass-A block
#define NREP 4             // counter replicas (wave-groups) to cut atomic depth

// 1/sqrt(1 + 1e-3)  (BN inference, moving mean 0 / var 1)
#define BN_INV 0.999500374750f

typedef _Float16 h8 __attribute__((ext_vector_type(8)));
typedef _Float16 h2 __attribute__((ext_vector_type(2)));
typedef float f32x4 __attribute__((ext_vector_type(4)));
typedef unsigned int u32x2 __attribute__((ext_vector_type(2)));

__device__ __forceinline__ float softplus_f(float x) {
    return fmaxf(x, 0.f) + __logf(1.f + __expf(-fabsf(x)));
}

// ---- K_pre: fused passA + embed + setup. Block roles:
//   [0, nbA)             passA: 1-atomic bucket sort, TRANSPOSED replicated
//                        counters (bank = key%32, no bank compression)
//   [nbA, +nbE)          embed: THREAD-per-node (1024 nodes/block, VALU-dense)
//   [.., +9)             LUT: inline wsum/bsum, 1024 entries/block
//   [.., +3)             weight swizzle Wsw + b2p
__global__ __launch_bounds__(1024)
void k_pre(const float* __restrict__ x, const float* __restrict__ emb_W,
           const float* __restrict__ emb_b, _Float16* __restrict__ h0,
           const float* __restrict__ fW1, const float* __restrict__ fb1,
           const float* __restrict__ fW2, const float* __restrict__ fb2,
           const float* __restrict__ iW1, const float* __restrict__ iW2,
           const float* __restrict__ bn_g, const float* __restrict__ bn_b,
           const float* __restrict__ ib2, h8* __restrict__ Wsw,
           float* __restrict__ b2p, float* __restrict__ lut,
           const int* __restrict__ ei, const float* __restrict__ dist,
           unsigned int* __restrict__ cursor, u32x2* __restrict__ stg,
           int N, int E, int NB, int nbA, int nbE) {
    __shared__ u32x2 s_rec[ABLK];              // 32KB block-local sorted records
    __shared__ unsigned s_cnt[NREP * NBMAX];   // 8KB transposed replicated counts
    __shared__ unsigned s_tot[NBMAX];          // scan -> bucket lstart
    __shared__ unsigned s_gst[NREP * NBMAX];   // per-(group,bucket) local starts
    __shared__ unsigned s_gbase[NBMAX];        // global bases (cursor-reserved)
    __shared__ float sW[FIN * H];              // 4KB emb weights (embed role)
    __shared__ float sB[H];
    __shared__ float swsum[64];
    __shared__ float sbsum;
    int b = blockIdx.x;
    int t = threadIdx.x;
    if (b < nbA) {
        // ---- passA role ----
        int e0 = b * ABLK;
        int nE = min(ABLK, E - e0);
        int gg = t >> 8;                       // wave-group 0..3
        for (int i = t; i < NREP * NBMAX; i += 1024) s_cnt[i] = 0;
        __syncthreads();
        int rowv[4];
        unsigned rxv[4] = {0u, 0u, 0u, 0u};
        unsigned rkv[4] = {0u, 0u, 0u, 0u};
#pragma unroll
        for (int j = 0; j < 4; j++) {
            int li = j * 1024 + t;
            rowv[j] = -1;
            if (li < nE) {
                int e = e0 + li;
                int r = ei[e];
                int col = ei[E + e];
                float d = dist[e];
                int didx = (int)(d * (32768.0f / CUTOFF) + 0.5f);
                didx = max(0, min(didx, 32767));
                rowv[j] = r;
                rxv[j] = ((unsigned)col << 15) | (unsigned)didx;
                rkv[j] = atomicAdd(&s_cnt[gg * NBMAX + r / BROWS], 1u);
            }
        }
        __syncthreads();
        unsigned tot = 0;
        if (t < NBMAX) {
            tot = s_cnt[t] + s_cnt[NBMAX + t] +
                  s_cnt[2 * NBMAX + t] + s_cnt[3 * NBMAX + t];
            s_tot[t] = tot;
        }
        __syncthreads();
        for (int off = 1; off < NBMAX; off <<= 1) {
            unsigned v = 0;
            if (t < NBMAX && t >= off) v = s_tot[t - off];
            __syncthreads();
            if (t < NBMAX) s_tot[t] += v;
            __syncthreads();
        }
        if (t < NBMAX) {
            unsigned lstart = s_tot[t] - tot;
            unsigned runb = lstart;
#pragma unroll
            for (int g = 0; g < NREP; g++) {
                s_gst[g * NBMAX + t] = runb;
                runb += s_cnt[g * NBMAX + t];
            }
            s_tot[t] = lstart;                 // repurpose as lstart
            s_gbase[t] = (tot && t < (unsigned)NB) ? atomicAdd(&cursor[t], tot) : 0u;
        }
        __syncthreads();
        // place from rank (NO atomic)
#pragma unroll
        for (int j = 0; j < 4; j++) {
            if (rowv[j] >= 0) {
                int bk = rowv[j] / BROWS;
                unsigned slot = s_gst[gg * NBMAX + bk] + rkv[j];
                u32x2 rec;
                rec.x = rxv[j];
                rec.y = (unsigned)rowv[j];
                s_rec[slot] = rec;
            }
        }
        __syncthreads();
        // linear walk of sorted records -> per-bucket contiguous global runs
        for (int i = t; i < nE; i += 1024) {
            u32x2 rec = s_rec[i];
            int bk = (int)(rec.y / BROWS);
            unsigned g = s_gbase[bk] + ((unsigned)i - s_tot[bk]);
            if (g < MAXC)                      // overflow guard (~never)
                stg[(size_t)bk * MAXC + g] = rec;
        }
    } else if (b < nbA + nbE) {
        // ---- embed role: thread-per-node, weights in LDS ----
        if (t < FIN * H) sW[t] = emb_W[t];
        if (t < H) sB[t] = emb_b[t];
        __syncthreads();
        int node = (b - nbA) * 1024 + t;
        if (node < N) {
            const float4* x4 = (const float4*)(x) + (size_t)node * (FIN / 4);
            float4 q0 = x4[0], q1 = x4[1], q2 = x4[2], q3 = x4[3];
            float xr[FIN] = {q0.x, q0.y, q0.z, q0.w, q1.x, q1.y, q1.z, q1.w,
                             q2.x, q2.y, q2.z, q2.w, q3.x, q3.y, q3.z, q3.w};
            _Float16* hp = h0 + (size_t)node * H;
#pragma unroll
            for (int half = 0; half < 2; half++) {
                float acc[32];
#pragma unroll
                for (int c = 0; c < 32; c++) acc[c] = sB[half * 32 + c];
#pragma unroll
                for (int k = 0; k < FIN; k++) {
                    float xv = xr[k];
#pragma unroll
                    for (int c = 0; c < 32; c++)
                        acc[c] += xv * sW[k * H + half * 32 + c];
                }
#pragma unroll
                for (int c8 = 0; c8 < 4; c8++) {
                    h8 v;
#pragma unroll
                    for (int j = 0; j < 8; j++) v[j] = (_Float16)acc[c8 * 8 + j];
                    *(h8*)(hp + half * 32 + c8 * 8) = v;
                }
            }
        }
    } else if (b < nbA + nbE + NLAYERS * 3) {
        // ---- LUT role ----
        int lb = b - nbA - nbE;
        int l = lb / 3, part = lb % 3;
        if (t < 64) {
            float s = 0.f;
            for (int j = 0; j < H; j++) s += fW2[l * H * H + t * H + j];
            swsum[t] = s;
        }
        if (t == 64) {
            float s = 0.f;
            for (int j = 0; j < H; j++) s += fb2[l * H + j];
            sbsum = s;
        }
        __syncthreads();
        int i = part * 1024 + t;
        if (i <= LUTN) {
            float d = (float)i * (CUTOFF / (float)LUTN);
            float scaled = d * (2.0f / CUTOFF) - 1.0f;
            float cut = 0.5f * (__cosf(d * (3.14159265358979f / CUTOFF)) + 1.0f);
            if (d > CUTOFF) cut = 0.f;
            float s = 0.f;
            for (int hh = 0; hh < H; hh++) {
                int wi = l * H + hh;
                s += tanhf(scaled * fW1[wi] + fb1[wi]) * swsum[hh];
            }
            lut[l * LUTSTRIDE + i] = cut * (s + sbsum);
        }
    } else {
        // ---- weight swizzle role ----
        int tid = (b - nbA - nbE - NLAYERS * 3) * 1024 + t;
        if (tid < NLAYERS * H)
            b2p[tid] = ib2[tid] * BN_INV * bn_g[tid] + bn_b[tid];
        if (tid < NLAYERS * 2 * 8 * 64) {
            int lane = tid & 63;
            int frag = (tid >> 6) & 7;
            int mat  = (tid >> 9) & 1;
            int l    = tid >> 10;
            int kt = frag >> 2, nt = frag & 3;
            int n = nt * 16 + (lane & 15);
            int k0 = kt * 32 + (lane >> 4) * 8;
            const float* W = (mat ? iW2 : iW1) + l * H * H;
            float scale = mat ? BN_INV * bn_g[l * H + n] : 1.0f;
            h8 v;
#pragma unroll
            for (int j = 0; j < 8; j++) v[j] = (_Float16)(W[(k0 + j) * H + n] * scale);
            Wsw[tid] = v;
        }
    }
}

// Pass B: per-bucket counting sort + row_ptr. ONE atomic per record with
// TRANSPOSED replicated counters (bank = row%32); rank+scan placement.
__global__ __launch_bounds__(1024)
void k_passB(const u32x2* __restrict__ stg, const unsigned int* __restrict__ cursor,
             int* __restrict__ row_ptr, unsigned int* __restrict__ recs,
             int N, int NB) {
    __shared__ int s_bb[NBMAX];
    __shared__ unsigned s_c[NREP * BROWS];     // 4KB transposed replicated counts
    __shared__ unsigned s_t[BROWS];
    __shared__ unsigned s_g[NREP * BROWS];     // per-(group,row) starts
    __shared__ unsigned s_out[MAXC];           // 20KB
    int b = blockIdx.x, t = threadIdx.x;
    int gg = t >> 8;
    // bucket counts + redundant inclusive scan over NBMAX
    if (t < NBMAX) {
        int cb = 0;
        if (t < NB) cb = min((int)cursor[t], MAXC);
        s_bb[t] = cb;
    }
    __syncthreads();
    for (int off = 1; off < NBMAX; off <<= 1) {
        int v = 0;
        if (t < NBMAX && t >= off) v = s_bb[t - off];
        __syncthreads();
        if (t < NBMAX) s_bb[t] += v;
        __syncthreads();
    }
    int bbase = (b > 0) ? s_bb[b - 1] : 0;
    int cnt = s_bb[b] - bbase;
    int r0 = b * BROWS;
    int r1 = min(r0 + BROWS, N);
    int nrows = r1 - r0;
    const u32x2* mystg = stg + (size_t)b * MAXC;
    for (int i = t; i < NREP * BROWS; i += 1024) s_c[i] = 0;
    __syncthreads();
    // single stg read: count + remember record & rank (static-index regs)
    u32x2 myrec[5];
    unsigned myrk[5] = {0u, 0u, 0u, 0u, 0u};
    int nm = 0;
#pragma unroll
    for (int i = 0; i < 5; i++) {
        int idx = t + i * 1024;
        if (idx < cnt) {
            myrec[i] = mystg[idx];
            myrk[i] = atomicAdd(&s_c[gg * BROWS + ((int)myrec[i].y - r0)], 1u);
            nm = i + 1;
        }
    }
    __syncthreads();
    unsigned tot = 0;
    if (t < BROWS) {
        tot = s_c[t] + s_c[BROWS + t] + s_c[2 * BROWS + t] + s_c[3 * BROWS + t];
        s_t[t] = tot;
    }
    __syncthreads();
    for (int off = 1; off < BROWS; off <<= 1) {
        unsigned v = 0;
        if (t < BROWS && t >= off) v = s_t[t - off];
        __syncthreads();
        if (t < BROWS) s_t[t] += v;
        __syncthreads();
    }
    if (t < BROWS) {
        unsigned excl = s_t[t] - tot;
        if (t < nrows) row_ptr[r0 + t] = bbase + (int)excl;
        unsigned runb = excl;
#pragma unroll
        for (int g = 0; g < NREP; g++) {
            s_g[g * BROWS + t] = runb;
            runb += s_c[g * BROWS + t];
        }
    }
    if (b == NB - 1 && t == 0) row_ptr[N] = bbase + cnt;
    __syncthreads();
    // place from rank (NO atomic)
#pragma unroll
    for (int i = 0; i < 5; i++)
        if (i < nm) {
            unsigned slot = s_g[gg * BROWS + ((int)myrec[i].y - r0)] + myrk[i];
            s_out[slot] = myrec[i].x;
        }
    __syncthreads();
    for (int i = t; i < cnt; i += 1024)
        recs[bbase + i] = s_out[i];
}

// 4-edge clamped processing for one row: loads recs+h, lerps fv, accumulates.
#define PROC4(KK, SS, TT, ACC) do {                                          \
    int _lim = ((TT) > (SS)) ? (TT) - 1 : 0;                                 \
    int _ka = min((KK), _lim),     _kb = min((KK) + 1, _lim);                \
    int _kc = min((KK) + 2, _lim), _kd = min((KK) + 3, _lim);                \
    unsigned _ra = recs[_ka], _rb = recs[_kb];                               \
    unsigned _rc = recs[_kc], _rd = recs[_kd];                               \
    float _ta = (float)(_ra & 32767u) * (1.0f / 16.0f);                      \
    float _tb = (float)(_rb & 32767u) * (1.0f / 16.0f);                      \
    float _tc = (float)(_rc & 32767u) * (1.0f / 16.0f);                      \
    float _td = (float)(_rd & 32767u) * (1.0f / 16.0f);                      \
    int _ia = (int)_ta, _ib = (int)_tb, _ic = (int)_tc, _id = (int)_td;      \
    float _fa = s_lut[_ia], _fb = s_lut[_ib];                                \
    float _fc = s_lut[_ic], _fd = s_lut[_id];                                \
    float _va = _fa + (_ta - (float)_ia) * (s_lut[_ia + 1] - _fa);           \
    float _vb = _fb + (_tb - (float)_ib) * (s_lut[_ib + 1] - _fb);           \
    float _vc = _fc + (_tc - (float)_ic) * (s_lut[_ic + 1] - _fc);           \
    float _vd = _fd + (_td - (float)_id) * (s_lut[_id + 1] - _fd);           \
    _va = ((KK)     < (TT)) ? _va : 0.f;                                     \
    _vb = ((KK) + 1 < (TT)) ? _vb : 0.f;                                     \
    _vc = ((KK) + 2 < (TT)) ? _vc : 0.f;                                     \
    _vd = ((KK) + 3 < (TT)) ? _vd : 0.f;                                     \
    union { uint4 u; h2 v[4]; } _pa, _pb, _pc, _pd;                          \
    _pa.u = h4[(_ra >> 15) * 8u + (unsigned)ci];                             \
    _pb.u = h4[(_rb >> 15) * 8u + (unsigned)ci];                             \
    _pc.u = h4[(_rc >> 15) * 8u + (unsigned)ci];                             \
    _pd.u = h4[(_rd >> 15) * 8u + (unsigned)ci];                             \
    _Float16 _ha = (_Float16)_va, _hb = (_Float16)_vb;                       \
    _Float16 _hc = (_Float16)_vc, _hd = (_Float16)_vd;                       \
    h2 _aa = (h2){_ha, _ha}, _ab = (h2){_hb, _hb};                           \
    h2 _ac = (h2){_hc, _hc}, _ad = (h2){_hd, _hd};                           \
    _Pragma("unroll")                                                        \
    for (int _q = 0; _q < 4; _q++) (ACC)[_q] += _aa * _pa.v[_q];             \
    _Pragma("unroll")                                                        \
    for (int _q = 0; _q < 4; _q++) (ACC)[_q] += _ab * _pb.v[_q];             \
    _Pragma("unroll")                                                        \
    for (int _q = 0; _q < 4; _q++) (ACC)[_q] += _ac * _pc.v[_q];             \
    _Pragma("unroll")                                                        \
    for (int _q = 0; _q < 4; _q++) (ACC)[_q] += _ad * _pd.v[_q];             \
} while (0)

// Fused layer. Phase A: group-owns-TWO-rows interleaved — 8 groups x 8 lanes;
// each group walks BOTH its rows with 4-edge unroll each (8 independent
// rec->gather chains in flight per group). Phase B: 64x64x2 MLP as 16 MFMAs.
// last=1: skip h store, emit per-wave 64-channel partial sums for the mean.
__global__ __launch_bounds__(256, 6)
void k_layer(const int* __restrict__ row_ptr, const unsigned int* __restrict__ recs,
             const float* __restrict__ lutl, const h8* __restrict__ Wsw,
             const float* __restrict__ b1, const float* __restrict__ b2p,
             const _Float16* __restrict__ h_in, _Float16* __restrict__ h_out,
             float* __restrict__ pA, int N, int last) {
    __shared__ float s_lut[LUTN + 1];       // 8196 B
    __shared__ _Float16 sA[64 * ASTRIDE];   // 9216 B
    for (int i = threadIdx.x; i <= LUTN; i += 256) s_lut[i] = lutl[i];
    __syncthreads();

    int lane = threadIdx.x & 63;
    int w = threadIdx.x >> 6;
    int base = blockIdx.x * 64 + w * 16;    // this wave's 16 nodes
    int g = lane >> 3, ci = lane & 7;       // 8 groups x 8 lanes
    const uint4* h4 = (const uint4*)h_in;   // 8 halves per uint4; 8 per row

    // ---- phase A: two rows per group, interleaved ----
    {
        int node0 = base + g;
        int node1 = base + 8 + g;
        h2 acc0[4], acc1[4];
#pragma unroll
        for (int q = 0; q < 4; q++) {
            acc0[q] = (h2){(_Float16)0.f, (_Float16)0.f};
            acc1[q] = (h2){(_Float16)0.f, (_Float16)0.f};
        }
        int s0 = 0, t0 = 0, s1 = 0, t1 = 0;
        if (node0 < N) { s0 = row_ptr[node0]; t0 = row_ptr[node0 + 1]; }
        if (node1 < N) { s1 = row_ptr[node1]; t1 = row_ptr[node1 + 1]; }
        int it0 = (t0 - s0 + 3) >> 2;
        int it1 = (t1 - s1 + 3) >> 2;
        int iters = max(it0, it1);
        for (int it = 0; it < iters; ++it) {
            int k0 = s0 + it * 4;
            int k1 = s1 + it * 4;
            PROC4(k0, s0, t0, acc0);
            PROC4(k1, s1, t1, acc1);
        }
        union { uint4 u4; h2 v[4]; } pk;
#pragma unroll
        for (int q = 0; q < 4; q++) pk.v[q] = acc0[q];
        *(uint4*)&sA[(size_t)(w * 16 + g) * ASTRIDE + ci * 8] = pk.u4;
#pragma unroll
        for (int q = 0; q < 4; q++) pk.v[q] = acc1[q];
        *(uint4*)&sA[(size_t)(w * 16 + 8 + g) * ASTRIDE + ci * 8] = pk.u4;
    }
    // wave-private LDS rows: in-wave ds ordering, no barrier needed

    // ---- phase B: MFMA MLP ----
    int q4 = lane >> 4, c16 = lane & 15;
    int rowb = w * 16;
    const h8* WB1 = Wsw;            // frags [kt][nt][lane]
    const h8* WB2 = Wsw + 8 * 64;
    h8 A0 = *(const h8*)&sA[(size_t)(rowb + c16) * ASTRIDE + q4 * 8];
    h8 A1 = *(const h8*)&sA[(size_t)(rowb + c16) * ASTRIDE + 32 + q4 * 8];
    f32x4 C1[4];
#pragma unroll
    for (int nt = 0; nt < 4; nt++) {
        f32x4 c = {0.f, 0.f, 0.f, 0.f};
        c = __builtin_amdgcn_mfma_f32_16x16x32_f16(A0, WB1[nt * 64 + lane], c, 0, 0, 0);
        c = __builtin_amdgcn_mfma_f32_16x16x32_f16(A1, WB1[(4 + nt) * 64 + lane], c, 0, 0, 0);
        C1[nt] = c;
    }
#pragma unroll
    for (int nt = 0; nt < 4; nt++) {
        float bb = b1[nt * 16 + c16];
#pragma unroll
        for (int reg = 0; reg < 4; reg++) {
            float v = softplus_f(C1[nt][reg] + bb);
            sA[(size_t)(rowb + q4 * 4 + reg) * ASTRIDE + nt * 16 + c16] = (_Float16)v;
        }
    }
    h8 M0 = *(const h8*)&sA[(size_t)(rowb + c16) * ASTRIDE + q4 * 8];
    h8 M1 = *(const h8*)&sA[(size_t)(rowb + c16) * ASTRIDE + 32 + q4 * 8];
    f32x4 C2[4];
#pragma unroll
    for (int nt = 0; nt < 4; nt++) {
        f32x4 c = {0.f, 0.f, 0.f, 0.f};
        c = __builtin_amdgcn_mfma_f32_16x16x32_f16(M0, WB2[nt * 64 + lane], c, 0, 0, 0);
        c = __builtin_amdgcn_mfma_f32_16x16x32_f16(M1, WB2[(4 + nt) * 64 + lane], c, 0, 0, 0);
        C2[nt] = c;
    }
    // epilogue: + b2' (BN folded), fp16 residual
    if (!last) {
#pragma unroll
        for (int nt = 0; nt < 4; nt++) {
            float bb2 = b2p[nt * 16 + c16];
#pragma unroll
            for (int reg = 0; reg < 4; reg++) {
                int node = base + q4 * 4 + reg;
                if (node < N) {
                    size_t idx = (size_t)node * H + nt * 16 + c16;
                    float hn = (float)h_in[idx] + C2[nt][reg] + bb2;
                    h_out[idx] = (_Float16)hn;
                }
            }
        }
    } else {
        // last layer: per-wave column partial sums (no h store)
        float ps[4];
#pragma unroll
        for (int nt = 0; nt < 4; nt++) {
            float bb2 = b2p[nt * 16 + c16];
            float s = 0.f;
#pragma unroll
            for (int reg = 0; reg < 4; reg++) {
                int node = base + q4 * 4 + reg;
                if (node < N) {
                    size_t idx = (size_t)node * H + nt * 16 + c16;
                    s += (float)h_in[idx] + C2[nt][reg] + bb2;
                }
            }
            ps[nt] = s;
        }
#pragma unroll
        for (int nt = 0; nt < 4; nt++) {
            float v = ps[nt];
            v += __shfl_xor(v, 16, 64);
            v += __shfl_xor(v, 32, 64);
            if (lane < 16)
                pA[((size_t)blockIdx.x * 4 + w) * H + nt * 16 + c16] = v;
        }
    }
}

// Stage 1 of mean: reduce per-wave partials (P rows) to MEANB rows.
__global__ __launch_bounds__(256)
void k_mean(const float* __restrict__ pA, float* __restrict__ partials, int P) {
    __shared__ float s_r[4][H];
    int lane = threadIdx.x & 63;
    int w = threadIdx.x >> 6;
    int wg = blockIdx.x * 4 + w;
    int stride = gridDim.x * 4;
    float local = 0.f;
    for (int i = wg; i < P; i += stride) local += pA[(size_t)i * H + lane];
    s_r[w][lane] = local;
    __syncthreads();
    if (w == 0) {
        float s = s_r[0][lane] + s_r[1][lane] + s_r[2][lane] + s_r[3][lane];
        partials[(size_t)blockIdx.x * H + lane] = s;
    }
}

// Stage 2: one block reduces MEANB partial rows, then the tiny output MLP.
__global__ __launch_bounds__(256)
void k_final(const float* __restrict__ partials, int N,
             const float* __restrict__ oW1, const float* __restrict__ ob1,
             const float* __restrict__ og1, const float* __restrict__ obt1,
             const float* __restrict__ oW2, const float* __restrict__ ob2,
             const float* __restrict__ og2, const float* __restrict__ obt2,
             const float* __restrict__ fin_W, const float* __restrict__ fin_b,
             float* __restrict__ out) {
    __shared__ float red[4][H];
    __shared__ float sg[H], su[H / 2], sv[H / 2];
    int t = threadIdx.x;
    int ch = t & 63, grp = t >> 6;
    float s = 0.f;
    for (int b = grp; b < MEANB; b += 4) s += partials[(size_t)b * H + ch];
    red[grp][ch] = s;
    __syncthreads();
    if (t < H) sg[t] = (red[0][t] + red[1][t] + red[2][t] + red[3][t]) / (float)N;
    __syncthreads();
    int j = t;
    if (j < H / 2) {
        float acc = ob1[j];
        for (int k = 0; k < H; k++) acc += sg[k] * oW1[k * (H / 2) + j];
        su[j] = softplus_f(acc) * BN_INV * og1[j] + obt1[j];
    }
    __syncthreads();
    if (j < H / 2) {
        float acc = ob2[j];
        for (int k = 0; k < H / 2; k++) acc += su[k] * oW2[k * (H / 2) + j];
        sv[j] = softplus_f(acc) * BN_INV * og2[j] + obt2[j];
    }
    __syncthreads();
    if (j < 3) {
        float acc = fin_b[j];
        for (int k = 0; k < H / 2; k++) acc += sv[k] * fin_W[k * 3 + j];
        out[j] = acc;
    }
}

extern "C" void kernel_launch(void* const* d_in, const int* in_sizes, int n_in,
                              void* d_out, int out_size, void* d_ws, size_t ws_size,
                              hipStream_t stream) {
    const float* x      = (const float*)d_in[0];
    const int*   ei     = (const int*)d_in[1];
    const float* dist   = (const float*)d_in[2];
    /* d_in[3] edge_attr: unused by reference */
    const float* emb_W  = (const float*)d_in[4];
    const float* emb_b  = (const float*)d_in[5];
    const float* fW1    = (const float*)d_in[6];
    const float* fb1    = (const float*)d_in[7];
    const float* fW2    = (const float*)d_in[8];
    const float* fb2    = (const float*)d_in[9];
    const float* iW1    = (const float*)d_in[10];
    const float* ib1    = (const float*)d_in[11];
    const float* iW2    = (const float*)d_in[12];
    const float* ib2    = (const float*)d_in[13];
    const float* bn_g   = (const float*)d_in[14];
    const float* bn_b   = (const float*)d_in[15];
    const float* oW1    = (const float*)d_in[16];
    const float* ob1    = (const float*)d_in[17];
    const float* og1    = (const float*)d_in[18];
    const float* obt1   = (const float*)d_in[19];
    const float* oW2    = (const float*)d_in[20];
    const float* ob2    = (const float*)d_in[21];
    const float* og2    = (const float*)d_in[22];
    const float* obt2   = (const float*)d_in[23];
    const float* fin_W  = (const float*)d_in[24];
    const float* fin_b  = (const float*)d_in[25];
    float* out = (float*)d_out;

    int N = in_sizes[0] / FIN;
    int E = in_sizes[2];
    int NB = (N + BROWS - 1) / BROWS;          // sort buckets (391 @ N=100k)
    int nb_tile = (N + 63) / 64;
    int P = nb_tile * 4;                       // per-wave partial rows

    // workspace layout (16B-aligned chunks first)
    float*  ws   = (float*)d_ws;
    _Float16* h0 = (_Float16*)ws;                          // N*H fp16
    _Float16* h1 = h0 + (size_t)N * H;                     // N*H fp16
    unsigned int* recs = (unsigned int*)(h1 + (size_t)N * H);    // E uint32
    h8*     Wsw  = (h8*)(recs + E);                        // 3*2*8*64 h8
    float*  lut  = (float*)(Wsw + NLAYERS * 2 * 8 * 64);   // 3*LUTSTRIDE
    float*  partials = lut + 3 * LUTSTRIDE;                // MEANB*H
    float*  b2p  = partials + MEANB * H;                   // L*H
    float*  pA   = b2p + NLAYERS * H;                      // P*H
    u32x2*  stg  = (u32x2*)(pA + (size_t)P * H);           // NBMAX*MAXC u32x2
    int*    row_ptr = (int*)(stg + (size_t)NBMAX * MAXC);  // N+1
    unsigned int* cursor = (unsigned int*)(row_ptr + N + 1);     // NBMAX

    hipMemsetAsync(cursor, 0, NBMAX * sizeof(unsigned int), stream);

    int nbA = (E + ABLK - 1) / ABLK;
    int nbE = (N + 1023) / 1024;
    int nb_pre = nbA + nbE + NLAYERS * 3 + 3;
    k_pre<<<nb_pre, 1024, 0, stream>>>(x, emb_W, emb_b, h0,
                                       fW1, fb1, fW2, fb2, iW1, iW2,
                                       bn_g, bn_b, ib2, Wsw, b2p, lut,
                                       ei, dist, cursor, stg,
                                       N, E, NB, nbA, nbE);

    k_passB<<<NB, 1024, 0, stream>>>(stg, cursor, row_ptr, recs, N, NB);

    _Float16* hp[2] = {h0, h1};
    for (int l = 0; l < NLAYERS; l++) {
        k_layer<<<nb_tile, 256, 0, stream>>>(row_ptr, recs, lut + (size_t)l * LUTSTRIDE,
                                             Wsw + (size_t)l * 1024,
                                             ib1 + l * H, b2p + l * H,
                                             hp[l & 1], hp[(l + 1) & 1], pA, N,
                                             (l == NLAYERS - 1) ? 1 : 0);
    }

    k_mean<<<MEANB, 256, 0, stream>>>(pA, partials, P);
    k_final<<<1, 256, 0, stream>>>(partials, N, oW1, ob1, og1, obt1,
                                   oW2, ob2, og2, obt2, fin_W, fin_b, out);
}

// Round 18
// 298.824 us; speedup vs baseline: 1.1223x; 1.0022x over previous
//
#include <hip/hip_runtime.h>
#include <hip/hip_fp16.h>
#include <math.h>

#define CUTOFF 5.0f
#define H 64
#define FIN 16
#define NLAYERS 3
#define LUTN 2048          // intervals; table has LUTN+1 entries
#define LUTSTRIDE 2052     // padded per-layer stride
#define ASTRIDE 72         // LDS row stride in halves (144B, 16B-aligned)
#define MEANB 256          // blocks in mean pass (partials rows)
#define BROWS 256          // rows per sort bucket
#define NBMAX 512          // max buckets (N <= 128K)
#define MAXC 5120          // per-bucket stg stride AND LDS sort capacity (20KB)
#define ABLK 4096          // edges per pass-A block
#define NREP 4             // counter replicas in passA
#define SUB 8              // col sub-buckets per row (passB secondary key)
#define NKEY (BROWS * SUB) // 2048 composite keys
#define PREP 2             // counter replicas in passB

// 1/sqrt(1 + 1e-3)  (BN inference, moving mean 0 / var 1)
#define BN_INV 0.999500374750f

typedef _Float16 h8 __attribute__((ext_vector_type(8)));
typedef _Float16 h2 __attribute__((ext_vector_type(2)));
typedef float f32x4 __attribute__((ext_vector_type(4)));
typedef unsigned int u32x2 __attribute__((ext_vector_type(2)));

__device__ __forceinline__ float softplus_f(float x) {
    return fmaxf(x, 0.f) + __logf(1.f + __expf(-fabsf(x)));
}

// ---- K_pre: fused passA + embed + setup. Block roles:
//   [0, nbA)             passA: 1-atomic bucket sort, transposed repl. counters
//   [nbA, +nbE)          embed: THREAD-per-node (1024 nodes/block, VALU-dense)
//   [.., +9)             LUT: inline wsum/bsum, 1024 entries/block
//   [.., +3)             weight swizzle Wsw + b2p
__global__ __launch_bounds__(1024)
void k_pre(const float* __restrict__ x, const float* __restrict__ emb_W,
           const float* __restrict__ emb_b, _Float16* __restrict__ h0,
           const float* __restrict__ fW1, const float* __restrict__ fb1,
           const float* __restrict__ fW2, const float* __restrict__ fb2,
           const float* __restrict__ iW1, const float* __restrict__ iW2,
           const float* __restrict__ bn_g, const float* __restrict__ bn_b,
           const float* __restrict__ ib2, h8* __restrict__ Wsw,
           float* __restrict__ b2p, float* __restrict__ lut,
           const int* __restrict__ ei, const float* __restrict__ dist,
           unsigned int* __restrict__ cursor, u32x2* __restrict__ stg,
           int N, int E, int NB, int nbA, int nbE) {
    __shared__ u32x2 s_rec[ABLK];              // 32KB block-local sorted records
    __shared__ unsigned s_cnt[NREP * NBMAX];   // 8KB transposed replicated counts
    __shared__ unsigned s_tot[NBMAX];          // scan -> bucket lstart
    __shared__ unsigned s_gst[NREP * NBMAX];   // per-(group,bucket) local starts
    __shared__ unsigned s_gbase[NBMAX];        // global bases (cursor-reserved)
    __shared__ float sW[FIN * H];              // 4KB emb weights (embed role)
    __shared__ float sB[H];
    __shared__ float swsum[64];
    __shared__ float sbsum;
    int b = blockIdx.x;
    int t = threadIdx.x;
    if (b < nbA) {
        // ---- passA role ----
        int e0 = b * ABLK;
        int nE = min(ABLK, E - e0);
        int gg = t >> 8;                       // wave-group 0..3
        for (int i = t; i < NREP * NBMAX; i += 1024) s_cnt[i] = 0;
        __syncthreads();
        int rowv[4];
        unsigned rxv[4] = {0u, 0u, 0u, 0u};
        unsigned rkv[4] = {0u, 0u, 0u, 0u};
#pragma unroll
        for (int j = 0; j < 4; j++) {
            int li = j * 1024 + t;
            rowv[j] = -1;
            if (li < nE) {
                int e = e0 + li;
                int r = ei[e];
                int col = ei[E + e];
                float d = dist[e];
                int didx = (int)(d * (32768.0f / CUTOFF) + 0.5f);
                didx = max(0, min(didx, 32767));
                rowv[j] = r;
                rxv[j] = ((unsigned)col << 15) | (unsigned)didx;
                rkv[j] = atomicAdd(&s_cnt[gg * NBMAX + r / BROWS], 1u);
            }
        }
        __syncthreads();
        unsigned tot = 0;
        if (t < NBMAX) {
            tot = s_cnt[t] + s_cnt[NBMAX + t] +
                  s_cnt[2 * NBMAX + t] + s_cnt[3 * NBMAX + t];
            s_tot[t] = tot;
        }
        __syncthreads();
        for (int off = 1; off < NBMAX; off <<= 1) {
            unsigned v = 0;
            if (t < NBMAX && t >= off) v = s_tot[t - off];
            __syncthreads();
            if (t < NBMAX) s_tot[t] += v;
            __syncthreads();
        }
        if (t < NBMAX) {
            unsigned lstart = s_tot[t] - tot;
            unsigned runb = lstart;
#pragma unroll
            for (int g = 0; g < NREP; g++) {
                s_gst[g * NBMAX + t] = runb;
                runb += s_cnt[g * NBMAX + t];
            }
            s_tot[t] = lstart;                 // repurpose as lstart
            s_gbase[t] = (tot && t < (unsigned)NB) ? atomicAdd(&cursor[t], tot) : 0u;
        }
        __syncthreads();
        // place from rank (NO atomic)
#pragma unroll
        for (int j = 0; j < 4; j++) {
            if (rowv[j] >= 0) {
                int bk = rowv[j] / BROWS;
                unsigned slot = s_gst[gg * NBMAX + bk] + rkv[j];
                u32x2 rec;
                rec.x = rxv[j];
                rec.y = (unsigned)rowv[j];
                s_rec[slot] = rec;
            }
        }
        __syncthreads();
        // linear walk of sorted records -> per-bucket contiguous global runs
        for (int i = t; i < nE; i += 1024) {
            u32x2 rec = s_rec[i];
            int bk = (int)(rec.y / BROWS);
            unsigned g = s_gbase[bk] + ((unsigned)i - s_tot[bk]);
            if (g < MAXC)                      // overflow guard (~never)
                stg[(size_t)bk * MAXC + g] = rec;
        }
    } else if (b < nbA + nbE) {
        // ---- embed role: thread-per-node, weights in LDS ----
        if (t < FIN * H) sW[t] = emb_W[t];
        if (t < H) sB[t] = emb_b[t];
        __syncthreads();
        int node = (b - nbA) * 1024 + t;
        if (node < N) {
            const float4* x4 = (const float4*)(x) + (size_t)node * (FIN / 4);
            float4 q0 = x4[0], q1 = x4[1], q2 = x4[2], q3 = x4[3];
            float xr[FIN] = {q0.x, q0.y, q0.z, q0.w, q1.x, q1.y, q1.z, q1.w,
                             q2.x, q2.y, q2.z, q2.w, q3.x, q3.y, q3.z, q3.w};
            _Float16* hp = h0 + (size_t)node * H;
#pragma unroll
            for (int half = 0; half < 2; half++) {
                float acc[32];
#pragma unroll
                for (int c = 0; c < 32; c++) acc[c] = sB[half * 32 + c];
#pragma unroll
                for (int k = 0; k < FIN; k++) {
                    float xv = xr[k];
#pragma unroll
                    for (int c = 0; c < 32; c++)
                        acc[c] += xv * sW[k * H + half * 32 + c];
                }
#pragma unroll
                for (int c8 = 0; c8 < 4; c8++) {
                    h8 v;
#pragma unroll
                    for (int j = 0; j < 8; j++) v[j] = (_Float16)acc[c8 * 8 + j];
                    *(h8*)(hp + half * 32 + c8 * 8) = v;
                }
            }
        }
    } else if (b < nbA + nbE + NLAYERS * 3) {
        // ---- LUT role ----
        int lb = b - nbA - nbE;
        int l = lb / 3, part = lb % 3;
        if (t < 64) {
            float s = 0.f;
            for (int j = 0; j < H; j++) s += fW2[l * H * H + t * H + j];
            swsum[t] = s;
        }
        if (t == 64) {
            float s = 0.f;
            for (int j = 0; j < H; j++) s += fb2[l * H + j];
            sbsum = s;
        }
        __syncthreads();
        int i = part * 1024 + t;
        if (i <= LUTN) {
            float d = (float)i * (CUTOFF / (float)LUTN);
            float scaled = d * (2.0f / CUTOFF) - 1.0f;
            float cut = 0.5f * (__cosf(d * (3.14159265358979f / CUTOFF)) + 1.0f);
            if (d > CUTOFF) cut = 0.f;
            float s = 0.f;
            for (int hh = 0; hh < H; hh++) {
                int wi = l * H + hh;
                s += tanhf(scaled * fW1[wi] + fb1[wi]) * swsum[hh];
            }
            lut[l * LUTSTRIDE + i] = cut * (s + sbsum);
        }
    } else {
        // ---- weight swizzle role ----
        int tid = (b - nbA - nbE - NLAYERS * 3) * 1024 + t;
        if (tid < NLAYERS * H)
            b2p[tid] = ib2[tid] * BN_INV * bn_g[tid] + bn_b[tid];
        if (tid < NLAYERS * 2 * 8 * 64) {
            int lane = tid & 63;
            int frag = (tid >> 6) & 7;
            int mat  = (tid >> 9) & 1;
            int l    = tid >> 10;
            int kt = frag >> 2, nt = frag & 3;
            int n = nt * 16 + (lane & 15);
            int k0 = kt * 32 + (lane >> 4) * 8;
            const float* W = (mat ? iW2 : iW1) + l * H * H;
            float scale = mat ? BN_INV * bn_g[l * H + n] : 1.0f;
            h8 v;
#pragma unroll
            for (int j = 0; j < 8; j++) v[j] = (_Float16)(W[(k0 + j) * H + n] * scale);
            Wsw[tid] = v;
        }
    }
}

// Pass B: per-bucket counting sort by composite key (row, col>>14) ->
// within-row edges come out in ascending col-range order (gather locality
// for k_layer). ONE atomic per record, transposed replicated counters,
// rank+scan placement. row_ptr = start of row's first sub-key.
__global__ __launch_bounds__(1024)
void k_passB(const u32x2* __restrict__ stg, const unsigned int* __restrict__ cursor,
             int* __restrict__ row_ptr, unsigned int* __restrict__ recs,
             int N, int NB) {
    __shared__ int s_bb[NBMAX];                // 2KB
    __shared__ unsigned s_c[PREP * NKEY];      // 16KB transposed repl. counts
    __shared__ unsigned s_t[NKEY];             // 8KB scan
    __shared__ unsigned s_g[PREP * NKEY];      // 16KB per-(group,key) starts
    __shared__ unsigned s_out[MAXC];           // 20KB
    int b = blockIdx.x, t = threadIdx.x;
    int gg = t >> 9;                           // 0..1
    // bucket counts + redundant inclusive scan over NBMAX
    if (t < NBMAX) {
        int cb = 0;
        if (t < NB) cb = min((int)cursor[t], MAXC);
        s_bb[t] = cb;
    }
    __syncthreads();
    for (int off = 1; off < NBMAX; off <<= 1) {
        int v = 0;
        if (t < NBMAX && t >= off) v = s_bb[t - off];
        __syncthreads();
        if (t < NBMAX) s_bb[t] += v;
        __syncthreads();
    }
    int bbase = (b > 0) ? s_bb[b - 1] : 0;
    int cnt = s_bb[b] - bbase;
    int r0 = b * BROWS;
    int r1 = min(r0 + BROWS, N);
    int nrows = r1 - r0;
    const u32x2* mystg = stg + (size_t)b * MAXC;
    for (int i = t; i < PREP * NKEY; i += 1024) s_c[i] = 0;
    __syncthreads();
    // single stg read: count + remember record & rank (static-index regs)
    u32x2 myrec[5];
    unsigned myrk[5] = {0u, 0u, 0u, 0u, 0u};
    int nm = 0;
#pragma unroll
    for (int i = 0; i < 5; i++) {
        int idx = t + i * 1024;
        if (idx < cnt) {
            myrec[i] = mystg[idx];
            int key = ((int)myrec[i].y - r0) * SUB + (int)(myrec[i].x >> 29);
            myrk[i] = atomicAdd(&s_c[gg * NKEY + key], 1u);
            nm = i + 1;
        }
    }
    __syncthreads();
    // totals + inclusive scan over NKEY (2 entries/thread, Hillis-Steele)
    int k0 = t, k1 = t + 1024;
    unsigned tot0 = s_c[k0] + s_c[NKEY + k0];
    unsigned tot1 = s_c[k1] + s_c[NKEY + k1];
    s_t[k0] = tot0;
    s_t[k1] = tot1;
    __syncthreads();
    for (int off = 1; off < NKEY; off <<= 1) {
        unsigned v0 = (k0 >= off) ? s_t[k0 - off] : 0u;
        unsigned v1 = (k1 >= off) ? s_t[k1 - off] : 0u;
        __syncthreads();
        s_t[k0] += v0;
        s_t[k1] += v1;
        __syncthreads();
    }
    // exclusive per-key starts -> per-(group,key) starts
    {
        unsigned e0 = s_t[k0] - tot0;
        unsigned e1 = s_t[k1] - tot1;
        s_g[k0] = e0;
        s_g[NKEY + k0] = e0 + s_c[k0];
        s_g[k1] = e1;
        s_g[NKEY + k1] = e1 + s_c[k1];
    }
    __syncthreads();
    // row_ptr = start of row's first sub-key (group 0)
    if (t < nrows) row_ptr[r0 + t] = bbase + (int)s_g[t * SUB];
    if (b == NB - 1 && t == 0) row_ptr[N] = bbase + cnt;
    // place from rank (NO atomic)
#pragma unroll
    for (int i = 0; i < 5; i++)
        if (i < nm) {
            int key = ((int)myrec[i].y - r0) * SUB + (int)(myrec[i].x >> 29);
            unsigned slot = s_g[gg * NKEY + key] + myrk[i];
            s_out[slot] = myrec[i].x;
        }
    __syncthreads();
    for (int i = t; i < cnt; i += 1024)
        recs[bbase + i] = s_out[i];
}

// 4-edge clamped processing for one row: loads recs+h, lerps fv, accumulates.
#define PROC4(KK, SS, TT, ACC) do {                                          \
    int _lim = ((TT) > (SS)) ? (TT) - 1 : 0;                                 \
    int _ka = min((KK), _lim),     _kb = min((KK) + 1, _lim);                \
    int _kc = min((KK) + 2, _lim), _kd = min((KK) + 3, _lim);                \
    unsigned _ra = recs[_ka], _rb = recs[_kb];                               \
    unsigned _rc = recs[_kc], _rd = recs[_kd];                               \
    float _ta = (float)(_ra & 32767u) * (1.0f / 16.0f);                      \
    float _tb = (float)(_rb & 32767u) * (1.0f / 16.0f);                      \
    float _tc = (float)(_rc & 32767u) * (1.0f / 16.0f);                      \
    float _td = (float)(_rd & 32767u) * (1.0f / 16.0f);                      \
    int _ia = (int)_ta, _ib = (int)_tb, _ic = (int)_tc, _id = (int)_td;      \
    float _fa = s_lut[_ia], _fb = s_lut[_ib];                                \
    float _fc = s_lut[_ic], _fd = s_lut[_id];                                \
    float _va = _fa + (_ta - (float)_ia) * (s_lut[_ia + 1] - _fa);           \
    float _vb = _fb + (_tb - (float)_ib) * (s_lut[_ib + 1] - _fb);           \
    float _vc = _fc + (_tc - (float)_ic) * (s_lut[_ic + 1] - _fc);           \
    float _vd = _fd + (_td - (float)_id) * (s_lut[_id + 1] - _fd);           \
    _va = ((KK)     < (TT)) ? _va : 0.f;                                     \
    _vb = ((KK) + 1 < (TT)) ? _vb : 0.f;                                     \
    _vc = ((KK) + 2 < (TT)) ? _vc : 0.f;                                     \
    _vd = ((KK) + 3 < (TT)) ? _vd : 0.f;                                     \
    union { uint4 u; h2 v[4]; } _pa, _pb, _pc, _pd;                          \
    _pa.u = h4[(_ra >> 15) * 8u + (unsigned)ci];                             \
    _pb.u = h4[(_rb >> 15) * 8u + (unsigned)ci];                             \
    _pc.u = h4[(_rc >> 15) * 8u + (unsigned)ci];                             \
    _pd.u = h4[(_rd >> 15) * 8u + (unsigned)ci];                             \
    _Float16 _ha = (_Float16)_va, _hb = (_Float16)_vb;                       \
    _Float16 _hc = (_Float16)_vc, _hd = (_Float16)_vd;                       \
    h2 _aa = (h2){_ha, _ha}, _ab = (h2){_hb, _hb};                           \
    h2 _ac = (h2){_hc, _hc}, _ad = (h2){_hd, _hd};                           \
    _Pragma("unroll")                                                        \
    for (int _q = 0; _q < 4; _q++) (ACC)[_q] += _aa * _pa.v[_q];             \
    _Pragma("unroll")                                                        \
    for (int _q = 0; _q < 4; _q++) (ACC)[_q] += _ab * _pb.v[_q];             \
    _Pragma("unroll")                                                        \
    for (int _q = 0; _q < 4; _q++) (ACC)[_q] += _ac * _pc.v[_q];             \
    _Pragma("unroll")                                                        \
    for (int _q = 0; _q < 4; _q++) (ACC)[_q] += _ad * _pd.v[_q];             \
} while (0)

// Fused layer. Phase A: group-owns-TWO-rows interleaved — 8 groups x 8 lanes;
// each group walks BOTH its rows with 4-edge unroll each (8 independent
// rec->gather chains in flight per group; edges now col-ordered within row
// for L2 gather locality). Phase B: 64x64x2 MLP as 16 MFMAs.
// last=1: skip h store, emit per-wave 64-channel partial sums for the mean.
__global__ __launch_bounds__(256, 6)
void k_layer(const int* __restrict__ row_ptr, const unsigned int* __restrict__ recs,
             const float* __restrict__ lutl, const h8* __restrict__ Wsw,
             const float* __restrict__ b1, const float* __restrict__ b2p,
             const _Float16* __restrict__ h_in, _Float16* __restrict__ h_out,
             float* __restrict__ pA, int N, int last) {
    __shared__ float s_lut[LUTN + 1];       // 8196 B
    __shared__ _Float16 sA[64 * ASTRIDE];   // 9216 B
    for (int i = threadIdx.x; i <= LUTN; i += 256) s_lut[i] = lutl[i];
    __syncthreads();

    int lane = threadIdx.x & 63;
    int w = threadIdx.x >> 6;
    int base = blockIdx.x * 64 + w * 16;    // this wave's 16 nodes
    int g = lane >> 3, ci = lane & 7;       // 8 groups x 8 lanes
    const uint4* h4 = (const uint4*)h_in;   // 8 halves per uint4; 8 per row

    // ---- phase A: two rows per group, interleaved ----
    {
        int node0 = base + g;
        int node1 = base + 8 + g;
        h2 acc0[4], acc1[4];
#pragma unroll
        for (int q = 0; q < 4; q++) {
            acc0[q] = (h2){(_Float16)0.f, (_Float16)0.f};
            acc1[q] = (h2){(_Float16)0.f, (_Float16)0.f};
        }
        int s0 = 0, t0 = 0, s1 = 0, t1 = 0;
        if (node0 < N) { s0 = row_ptr[node0]; t0 = row_ptr[node0 + 1]; }
        if (node1 < N) { s1 = row_ptr[node1]; t1 = row_ptr[node1 + 1]; }
        int it0 = (t0 - s0 + 3) >> 2;
        int it1 = (t1 - s1 + 3) >> 2;
        int iters = max(it0, it1);
        for (int it = 0; it < iters; ++it) {
            int k0 = s0 + it * 4;
            int k1 = s1 + it * 4;
            PROC4(k0, s0, t0, acc0);
            PROC4(k1, s1, t1, acc1);
        }
        union { uint4 u4; h2 v[4]; } pk;
#pragma unroll
        for (int q = 0; q < 4; q++) pk.v[q] = acc0[q];
        *(uint4*)&sA[(size_t)(w * 16 + g) * ASTRIDE + ci * 8] = pk.u4;
#pragma unroll
        for (int q = 0; q < 4; q++) pk.v[q] = acc1[q];
        *(uint4*)&sA[(size_t)(w * 16 + 8 + g) * ASTRIDE + ci * 8] = pk.u4;
    }
    // wave-private LDS rows: in-wave ds ordering, no barrier needed

    // ---- phase B: MFMA MLP ----
    int q4 = lane >> 4, c16 = lane & 15;
    int rowb = w * 16;
    const h8* WB1 = Wsw;            // frags [kt][nt][lane]
    const h8* WB2 = Wsw + 8 * 64;
    h8 A0 = *(const h8*)&sA[(size_t)(rowb + c16) * ASTRIDE + q4 * 8];
    h8 A1 = *(const h8*)&sA[(size_t)(rowb + c16) * ASTRIDE + 32 + q4 * 8];
    f32x4 C1[4];
#pragma unroll
    for (int nt = 0; nt < 4; nt++) {
        f32x4 c = {0.f, 0.f, 0.f, 0.f};
        c = __builtin_amdgcn_mfma_f32_16x16x32_f16(A0, WB1[nt * 64 + lane], c, 0, 0, 0);
        c = __builtin_amdgcn_mfma_f32_16x16x32_f16(A1, WB1[(4 + nt) * 64 + lane], c, 0, 0, 0);
        C1[nt] = c;
    }
#pragma unroll
    for (int nt = 0; nt < 4; nt++) {
        float bb = b1[nt * 16 + c16];
#pragma unroll
        for (int reg = 0; reg < 4; reg++) {
            float v = softplus_f(C1[nt][reg] + bb);
            sA[(size_t)(rowb + q4 * 4 + reg) * ASTRIDE + nt * 16 + c16] = (_Float16)v;
        }
    }
    h8 M0 = *(const h8*)&sA[(size_t)(rowb + c16) * ASTRIDE + q4 * 8];
    h8 M1 = *(const h8*)&sA[(size_t)(rowb + c16) * ASTRIDE + 32 + q4 * 8];
    f32x4 C2[4];
#pragma unroll
    for (int nt = 0; nt < 4; nt++) {
        f32x4 c = {0.f, 0.f, 0.f, 0.f};
        c = __builtin_amdgcn_mfma_f32_16x16x32_f16(M0, WB2[nt * 64 + lane], c, 0, 0, 0);
        c = __builtin_amdgcn_mfma_f32_16x16x32_f16(M1, WB2[(4 + nt) * 64 + lane], c, 0, 0, 0);
        C2[nt] = c;
    }
    // epilogue: + b2' (BN folded), fp16 residual
    if (!last) {
#pragma unroll
        for (int nt = 0; nt < 4; nt++) {
            float bb2 = b2p[nt * 16 + c16];
#pragma unroll
            for (int reg = 0; reg < 4; reg++) {
                int node = base + q4 * 4 + reg;
                if (node < N) {
                    size_t idx = (size_t)node * H + nt * 16 + c16;
                    float hn = (float)h_in[idx] + C2[nt][reg] + bb2;
                    h_out[idx] = (_Float16)hn;
                }
            }
        }
    } else {
        // last layer: per-wave column partial sums (no h store)
        float ps[4];
#pragma unroll
        for (int nt = 0; nt < 4; nt++) {
            float bb2 = b2p[nt * 16 + c16];
            float s = 0.f;
#pragma unroll
            for (int reg = 0; reg < 4; reg++) {
                int node = base + q4 * 4 + reg;
                if (node < N) {
                    size_t idx = (size_t)node * H + nt * 16 + c16;
                    s += (float)h_in[idx] + C2[nt][reg] + bb2;
                }
            }
            ps[nt] = s;
        }
#pragma unroll
        for (int nt = 0; nt < 4; nt++) {
            float v = ps[nt];
            v += __shfl_xor(v, 16, 64);
            v += __shfl_xor(v, 32, 64);
            if (lane < 16)
                pA[((size_t)blockIdx.x * 4 + w) * H + nt * 16 + c16] = v;
        }
    }
}

// Stage 1 of mean: reduce per-wave partials (P rows) to MEANB rows.
__global__ __launch_bounds__(256)
void k_mean(const float* __restrict__ pA, float* __restrict__ partials, int P) {
    __shared__ float s_r[4][H];
    int lane = threadIdx.x & 63;
    int w = threadIdx.x >> 6;
    int wg = blockIdx.x * 4 + w;
    int stride = gridDim.x * 4;
    float local = 0.f;
    for (int i = wg; i < P; i += stride) local += pA[(size_t)i * H + lane];
    s_r[w][lane] = local;
    __syncthreads();
    if (w == 0) {
        float s = s_r[0][lane] + s_r[1][lane] + s_r[2][lane] + s_r[3][lane];
        partials[(size_t)blockIdx.x * H + lane] = s;
    }
}

// Stage 2: one block reduces MEANB partial rows, then the tiny output MLP.
__global__ __launch_bounds__(256)
void k_final(const float* __restrict__ partials, int N,
             const float* __restrict__ oW1, const float* __restrict__ ob1,
             const float* __restrict__ og1, const float* __restrict__ obt1,
             const float* __restrict__ oW2, const float* __restrict__ ob2,
             const float* __restrict__ og2, const float* __restrict__ obt2,
             const float* __restrict__ fin_W, const float* __restrict__ fin_b,
             float* __restrict__ out) {
    __shared__ float red[4][H];
    __shared__ float sg[H], su[H / 2], sv[H / 2];
    int t = threadIdx.x;
    int ch = t & 63, grp = t >> 6;
    float s = 0.f;
    for (int b = grp; b < MEANB; b += 4) s += partials[(size_t)b * H + ch];
    red[grp][ch] = s;
    __syncthreads();
    if (t < H) sg[t] = (red[0][t] + red[1][t] + red[2][t] + red[3][t]) / (float)N;
    __syncthreads();
    int j = t;
    if (j < H / 2) {
        float acc = ob1[j];
        for (int k = 0; k < H; k++) acc += sg[k] * oW1[k * (H / 2) + j];
        su[j] = softplus_f(acc) * BN_INV * og1[j] + obt1[j];
    }
    __syncthreads();
    if (j < H / 2) {
        float acc = ob2[j];
        for (int k = 0; k < H / 2; k++) acc += su[k] * oW2[k * (H / 2) + j];
        sv[j] = softplus_f(acc) * BN_INV * og2[j] + obt2[j];
    }
    __syncthreads();
    if (j < 3) {
        float acc = fin_b[j];
        for (int k = 0; k < H / 2; k++) acc += sv[k] * fin_W[k * 3 + j];
        out[j] = acc;
    }
}

extern "C" void kernel_launch(void* const* d_in, const int* in_sizes, int n_in,
                              void* d_out, int out_size, void* d_ws, size_t ws_size,
                              hipStream_t stream) {
    const float* x      = (const float*)d_in[0];
    const int*   ei     = (const int*)d_in[1];
    const float* dist   = (const float*)d_in[2];
    /* d_in[3] edge_attr: unused by reference */
    const float* emb_W  = (const float*)d_in[4];
    const float* emb_b  = (const float*)d_in[5];
    const float* fW1    = (const float*)d_in[6];
    const float* fb1    = (const float*)d_in[7];
    const float* fW2    = (const float*)d_in[8];
    const float* fb2    = (const float*)d_in[9];
    const float* iW1    = (const float*)d_in[10];
    const float* ib1    = (const float*)d_in[11];
    const float* iW2    = (const float*)d_in[12];
    const float* ib2    = (const float*)d_in[13];
    const float* bn_g   = (const float*)d_in[14];
    const float* bn_b   = (const float*)d_in[15];
    const float* oW1    = (const float*)d_in[16];
    const float* ob1    = (const float*)d_in[17];
    const float* og1    = (const float*)d_in[18];
    const float* obt1   = (const float*)d_in[19];
    const float* oW2    = (const float*)d_in[20];
    const float* ob2    = (const float*)d_in[21];
    const float* og2    = (const float*)d_in[22];
    const float* obt2   = (const float*)d_in[23];
    const float* fin_W  = (const float*)d_in[24];
    const float* fin_b  = (const float*)d_in[25];
    float* out = (float*)d_out;

    int N = in_sizes[0] / FIN;
    int E = in_sizes[2];
    int NB = (N + BROWS - 1) / BROWS;          // sort buckets (391 @ N=100k)
    int nb_tile = (N + 63) / 64;
    int P = nb_tile * 4;                       // per-wave partial rows

    // workspace layout (16B-aligned chunks first)
    float*  ws   = (float*)d_ws;
    _Float16* h0 = (_Float16*)ws;                          // N*H fp16
    _Float16* h1 = h0 + (size_t)N * H;                     // N*H fp16
    unsigned int* recs = (unsigned int*)(h1 + (size_t)N * H);    // E uint32
    h8*     Wsw  = (h8*)(recs + E);                        // 3*2*8*64 h8
    float*  lut  = (float*)(Wsw + NLAYERS * 2 * 8 * 64);   // 3*LUTSTRIDE
    float*  partials = lut + 3 * LUTSTRIDE;                // MEANB*H
    float*  b2p  = partials + MEANB * H;                   // L*H
    float*  pA   = b2p + NLAYERS * H;                      // P*H
    u32x2*  stg  = (u32x2*)(pA + (size_t)P * H);           // NBMAX*MAXC u32x2
    int*    row_ptr = (int*)(stg + (size_t)NBMAX * MAXC);  // N+1
    unsigned int* cursor = (unsigned int*)(row_ptr + N + 1);     // NBMAX

    hipMemsetAsync(cursor, 0, NBMAX * sizeof(unsigned int), stream);

    int nbA = (E + ABLK - 1) / ABLK;
    int nbE = (N + 1023) / 1024;
    int nb_pre = nbA + nbE + NLAYERS * 3 + 3;
    k_pre<<<nb_pre, 1024, 0, stream>>>(x, emb_W, emb_b, h0,
                                       fW1, fb1, fW2, fb2, iW1, iW2,
                                       bn_g, bn_b, ib2, Wsw, b2p, lut,
                                       ei, dist, cursor, stg,
                                       N, E, NB, nbA, nbE);

    k_passB<<<NB, 1024, 0, stream>>>(stg, cursor, row_ptr, recs, N, NB);

    _Float16* hp[2] = {h0, h1};
    for (int l = 0; l < NLAYERS; l++) {
        k_layer<<<nb_tile, 256, 0, stream>>>(row_ptr, recs, lut + (size_t)l * LUTSTRIDE,
                                             Wsw + (size_t)l * 1024,
                                             ib1 + l * H, b2p + l * H,
                                             hp[l & 1], hp[(l + 1) & 1], pA, N,
                                             (l == NLAYERS - 1) ? 1 : 0);
    }

    k_mean<<<MEANB, 256, 0, stream>>>(pA, partials, P);
    k_final<<<1, 256, 0, stream>>>(partials, N, oW1, ob1, og1, obt1,
                                   oW2, ob2, og2, obt2, fin_W, fin_b, out);
}